// Round 9
// baseline (187.922 us; speedup 1.0000x reference)
//
#include <hip/hip_runtime.h>
#include <stdint.h>

typedef float  f32x4  __attribute__((ext_vector_type(4)));
typedef float  f32x16 __attribute__((ext_vector_type(16)));
typedef short  s16x8  __attribute__((ext_vector_type(8)));
typedef unsigned int u32x4 __attribute__((ext_vector_type(4)));
typedef unsigned short u16;
typedef u16    u16x4 __attribute__((ext_vector_type(4)));

#define SLEN 2048
#define HDIM 1024
#define NHEAD 16
#define DHEAD 64
#define BATCH 4
#define LOG2E 1.44269504088896340736f
#define SC2   0.18033688011111772f   /* 0.125 * log2(e) */
#define ISC2  5.5451774444795623f    /* 1/SC2 */

__device__ __forceinline__ u16 f2bf(float f) {
  uint32_t u = __builtin_bit_cast(uint32_t, f);
  u += 0x7FFFu + ((u >> 16) & 1u);
  return (u16)(u >> 16);
}

__device__ __forceinline__ uint32_t cvtpk2(float a, float b) {
  uint32_t r;
  asm("v_cvt_pk_bf16_f32 %0, %1, %2" : "=v"(r) : "v"(a), "v"(b));
  return r;
}

__device__ __forceinline__ void gld_lds16(const void* g, void* l) {
  __builtin_amdgcn_global_load_lds(
      (const __attribute__((address_space(1))) unsigned int*)g,
      (__attribute__((address_space(3))) unsigned int*)l, 16, 0, 0);
}

// ---- fused prep: HS->bf16, 3 weights scaled->bf16, m2, bqs, mask-zero flag ----
__global__ __launch_bounds__(256) void prep_all(
    const float4* __restrict__ hs, const float4* __restrict__ W0,
    const float4* __restrict__ W1, const float4* __restrict__ W2,
    const float* __restrict__ mask, const float* __restrict__ bq,
    u16* __restrict__ HSb, u16* __restrict__ O0, u16* __restrict__ O1,
    u16* __restrict__ O2, float* __restrict__ m2, float* __restrict__ bqs,
    float* __restrict__ flagp) {
  const int bid = blockIdx.x, tid = threadIdx.x;
  if (bid < 8192) {                       // hidden states: 8M elems
    int i = bid * 256 + tid;
    float4 v = hs[i];
    u16x4 o;
    o.x = f2bf(v.x); o.y = f2bf(v.y); o.z = f2bf(v.z); o.w = f2bf(v.w);
    *(u16x4*)(HSb + (size_t)i * 4) = o;
  } else if (bid < 11264) {               // 3 weight matrices
    int zz = (bid - 8192) >> 10;
    int i = ((bid - 8192) & 1023) * 256 + tid;
    const float4* in = zz == 0 ? W0 : (zz == 1 ? W1 : W2);
    u16* out = zz == 0 ? O0 : (zz == 1 ? O1 : O2);
    const float sc = zz == 0 ? SC2 : ISC2;
    float4 v = in[i];
    u16x4 o;
    o.x = f2bf(v.x * sc); o.y = f2bf(v.y * sc);
    o.z = f2bf(v.z * sc); o.w = f2bf(v.w * sc);
    *(u16x4*)(out + (size_t)i * 4) = o;
  } else if (bid < 11296) {               // m2 = mask*LOG2E (8192 floats)
    int i = (bid - 11264) * 256 + tid;
    m2[i] = mask[i] * LOG2E;
  } else if (bid < 11297) {               // bqs = bq*SC2 (1024 floats)
#pragma unroll
    for (int k = 0; k < 4; ++k) bqs[tid + k * 256] = bq[tid + k * 256] * SC2;
  } else {                                // mask nonzero flag (4 floats)
    float a = 0.f;
#pragma unroll
    for (int k = 0; k < 32; ++k) a += __builtin_fabsf(mask[tid + k * 256]);
    int nz = __any(a != 0.f) ? 1 : 0;
    if ((tid & 63) == 0) flagp[tid >> 6] = (float)nz;
  }
}

// ---------------- GEMM body: C[M,1024] = A @ W^T + bias, BK=64 ----------------
// MODE 0: row-major C. MODE 1: transposed-V layout Vt[(s>>11)*1024+col][s&2047]
__device__ __forceinline__ void gemm_body(const u16* __restrict__ A,
                                          const u16* __restrict__ W,
                                          const float* __restrict__ bias,
                                          u16* __restrict__ C, int mode) {
  __shared__ u16 As[128 * 64];
  __shared__ u16 Bs[128 * 64];
  const int tid = threadIdx.x;
  const int lane = tid & 63;
  const int w = tid >> 6;
  const int wr = w >> 1, wc = w & 1;
  const int brow = blockIdx.y * 128;
  const int bcol = blockIdx.x * 128;
  const int l15 = lane & 15, l4 = lane >> 4;
  const int koff = l4 * 8;

  f32x4 acc[4][4];
#pragma unroll
  for (int m = 0; m < 4; ++m)
#pragma unroll
    for (int n = 0; n < 4; ++n) acc[m][n] = f32x4{0.f, 0.f, 0.f, 0.f};

  for (int kt = 0; kt < HDIM / 64; ++kt) {
    __syncthreads();
#pragma unroll
    for (int it = 0; it < 4; ++it) {
      int c = tid + it * 256;         // 0..1023 16B-chunks
      int r = c >> 3, c8 = c & 7;
      gld_lds16(A + (size_t)(brow + r) * HDIM + kt * 64 + c8 * 8,
                (u16*)As + (size_t)c * 8);
      gld_lds16(W + (size_t)(bcol + r) * HDIM + kt * 64 + c8 * 8,
                (u16*)Bs + (size_t)c * 8);
    }
    __syncthreads();

#pragma unroll
    for (int kk = 0; kk < 2; ++kk) {
      s16x8 af[4], bfr[4];
#pragma unroll
      for (int m = 0; m < 4; ++m)
        af[m] = *(const s16x8*)(As + (size_t)(wr * 64 + m * 16 + l15) * 64 +
                                kk * 32 + koff);
#pragma unroll
      for (int n = 0; n < 4; ++n)
        bfr[n] = *(const s16x8*)(Bs + (size_t)(wc * 64 + n * 16 + l15) * 64 +
                                 kk * 32 + koff);
#pragma unroll
      for (int m = 0; m < 4; ++m)
#pragma unroll
        for (int n = 0; n < 4; ++n)
          acc[m][n] = __builtin_amdgcn_mfma_f32_16x16x32_bf16(af[m], bfr[n],
                                                              acc[m][n], 0, 0, 0);
    }
  }

#pragma unroll
  for (int n = 0; n < 4; ++n) {
    int col = bcol + wc * 64 + n * 16 + l15;
    float bv = bias[col];
#pragma unroll
    for (int m = 0; m < 4; ++m) {
      int row0 = brow + wr * 64 + m * 16 + l4 * 4;
      if (mode == 0) {
#pragma unroll
        for (int j = 0; j < 4; ++j)
          C[(size_t)(row0 + j) * HDIM + col] = f2bf(acc[m][n][j] + bv);
      } else {
        u16x4 o;
#pragma unroll
        for (int j = 0; j < 4; ++j) o[j] = f2bf(acc[m][n][j] + bv);
        *(u16x4*)(C + (size_t)(((row0 >> 11) << 10) + col) * SLEN +
                  (row0 & (SLEN - 1))) = o;
      }
    }
  }
}

__global__ __launch_bounds__(256) void gemm_bt(const u16* __restrict__ A,
                                               const u16* __restrict__ W,
                                               const float* __restrict__ bias,
                                               u16* __restrict__ C) {
  gemm_body(A, W, bias, C, 0);
}

__global__ __launch_bounds__(256) void gemm_kv(const u16* __restrict__ A,
                                               const u16* __restrict__ Wk,
                                               const float* __restrict__ bk,
                                               u16* __restrict__ K,
                                               const u16* __restrict__ Wv,
                                               const float* __restrict__ bv,
                                               u16* __restrict__ Vt) {
  if (blockIdx.z == 0) gemm_body(A, Wk, bk, K, 0);
  else                 gemm_body(A, Wv, bv, Vt, 1);
}

// ---------------- Flash attention v9 ----------------
// 32x32 MFMA, in-register P, MFMA row-sum; hoisted zero C-tuple; kb-loop
// unrolled x2 with compile-time buffer pointers (LICM of all LDS addresses).
__global__ __launch_bounds__(256, 4) void attn_kernel(
    const u16* __restrict__ Qs, const u16* __restrict__ Kb,
    const u16* __restrict__ Vtg, const float* __restrict__ m2g,
    const float* __restrict__ flagp, float* __restrict__ out) {
  __shared__ u16 Ks[2][64 * 64];
  __shared__ u16 Vts[2][64 * 64];

  const int tid = threadIdx.x;
  const int lane = tid & 63;
  const int w = tid >> 6;          // 0..3
  // XCD-chunked bijective swizzle (1024 % 8 == 0): 8 bh (=4MB K+V) per XCD
  const int bid = blockIdx.x;
  const int swz = (bid & 7) * 128 + (bid >> 3);
  const int qt = swz & 15;
  const int bh = swz >> 4;
  const int b = bh >> 4, h = bh & 15;
  const int l31 = lane & 31;
  const int h1 = lane >> 5;        // 0/1

  const float4 fl = *(const float4*)flagp;
  const bool mz = (fl.x == 0.f && fl.y == 0.f && fl.z == 0.f && fl.w == 0.f);

  // Q fragments (B-operand): lane holds Q[q0+l31][dch*16 + h1*8 .. +8]
  const int q0 = qt * 128 + w * 32;
  s16x8 qf[4];
  {
    const u16* qp = Qs + (size_t)(b * SLEN + q0 + l31) * HDIM + h * DHEAD + h1 * 8;
#pragma unroll
    for (int dch = 0; dch < 4; ++dch) qf[dch] = *(const s16x8*)(qp + dch * 16);
  }

  // ones fragment for row-sum MFMA (bf16 1.0 = 0x3F80)
  const s16x8 onesf = {(short)0x3F80, (short)0x3F80, (short)0x3F80,
                       (short)0x3F80, (short)0x3F80, (short)0x3F80,
                       (short)0x3F80, (short)0x3F80};

  // opaque zero C-tuple: built from a runtime value the compiler can't fold,
  // so it lives in 16 VGPRs once instead of 16 v_movs per MFMA C-init.
  const float zf = fl.x * 0.0f;
  f32x16 zc;
#pragma unroll
  for (int i = 0; i < 16; ++i) zc[i] = zf;

  // staging: 512 16B-chunks per 64x64 tile, 2 per thread
  const int r0 = tid >> 3, c0 = tid & 7;
  const int cl0 = c0 ^ (r0 & 7);
  const int r1 = r0 + 32;
  const int cl1 = c0 ^ (r1 & 7);
  const u16* Kbase = Kb + (size_t)(b * SLEN) * HDIM + h * DHEAD;
  const u16* Vbase = Vtg + (size_t)bh * 64 * SLEN;
  const float* mbase = m2g + b * SLEN;
  // hoisted per-lane staging base pointers
  const u16* KstA = Kbase + (size_t)r0 * HDIM + cl0 * 8;
  const u16* KstB = Kbase + (size_t)r1 * HDIM + cl1 * 8;
  const u16* VstA = Vbase + (size_t)r0 * SLEN + cl0 * 8;
  const u16* VstB = Vbase + (size_t)r1 * SLEN + cl1 * 8;

  f32x16 acc0{}, acc1{}, acc_s{};

  auto stage = [&](u16* Kd, u16* Vd, int kbn) {
    const size_t ko = (size_t)kbn * 64 * HDIM;
    const int vo = kbn * 64;
    gld_lds16(KstA + ko, Kd + tid * 8);
    gld_lds16(KstB + ko, Kd + (tid + 256) * 8);
    gld_lds16(VstA + vo, Vd + tid * 8);
    gld_lds16(VstB + vo, Vd + (tid + 256) * 8);
  };

  auto tile = [&](const u16* Kc, const u16* Vc, int kb) {
    uint32_t W[16];
#pragma unroll
    for (int kblk = 0; kblk < 2; ++kblk) {
      f32x16 cinit;
      if (mz) {
        cinit = zc;
      } else {
#pragma unroll
        for (int g = 0; g < 4; ++g) {
          float4 mk =
              *(const float4*)(mbase + kb * 64 + kblk * 32 + g * 8 + h1 * 4);
          cinit[4 * g + 0] = mk.x; cinit[4 * g + 1] = mk.y;
          cinit[4 * g + 2] = mk.z; cinit[4 * g + 3] = mk.w;
        }
      }
      const int row = kblk * 32 + l31;
      __builtin_amdgcn_s_setprio(1);
      f32x16 sT;
      {
        const int ch = h1 ^ (row & 7);
        s16x8 kf = *(const s16x8*)(Kc + row * 64 + ch * 8);
        sT = __builtin_amdgcn_mfma_f32_32x32x16_bf16(kf, qf[0], cinit, 0, 0, 0);
      }
#pragma unroll
      for (int dch = 1; dch < 4; ++dch) {
        const int ch = (dch * 2 + h1) ^ (row & 7);
        s16x8 kf = *(const s16x8*)(Kc + row * 64 + ch * 8);
        sT = __builtin_amdgcn_mfma_f32_32x32x16_bf16(kf, qf[dch], sT, 0, 0, 0);
      }
      __builtin_amdgcn_s_setprio(0);
      // lane holds S^T[k][q=l31] (log2 domain, mask included)
#pragma unroll
      for (int g = 0; g < 4; ++g) {
        float p0 = __builtin_amdgcn_exp2f(sT[4 * g + 0]);
        float p1 = __builtin_amdgcn_exp2f(sT[4 * g + 1]);
        float p2 = __builtin_amdgcn_exp2f(sT[4 * g + 2]);
        float p3 = __builtin_amdgcn_exp2f(sT[4 * g + 3]);
        W[kblk * 8 + 2 * g]     = cvtpk2(p0, p1);
        W[kblk * 8 + 2 * g + 1] = cvtpk2(p2, p3);
      }
    }

    // half-exchange across lane-32 boundary: one v_permlane32_swap_b32 per pair
#pragma unroll
    for (int c = 0; c < 4; ++c) {
#pragma unroll
      for (int e = 0; e < 2; ++e) {
        uint32_t a = W[4 * c + e], bb = W[4 * c + 2 + e];
        asm("v_permlane32_swap_b32 %0, %1" : "+v"(a), "+v"(bb));
        W[4 * c + e] = a;
        W[4 * c + 2 + e] = bb;
      }
    }

    // PV + row-sum: acc[db] += P-frag(c) x V-frag(db,c); acc_s += P-frag x ones
    __builtin_amdgcn_s_setprio(1);
#pragma unroll
    for (int c = 0; c < 4; ++c) {
      u32x4 t = {W[4 * c], W[4 * c + 1], W[4 * c + 2], W[4 * c + 3]};
      s16x8 af = __builtin_bit_cast(s16x8, t);
      const int ch = (c * 2 + h1) ^ (l31 & 7);
      s16x8 vf0 = *(const s16x8*)(Vc + l31 * 64 + ch * 8);
      s16x8 vf1 = *(const s16x8*)(Vc + (32 + l31) * 64 + ch * 8);
      acc0 = __builtin_amdgcn_mfma_f32_32x32x16_bf16(af, vf0, acc0, 0, 0, 0);
      acc1 = __builtin_amdgcn_mfma_f32_32x32x16_bf16(af, vf1, acc1, 0, 0, 0);
      acc_s = __builtin_amdgcn_mfma_f32_32x32x16_bf16(af, onesf, acc_s, 0, 0, 0);
    }
    __builtin_amdgcn_s_setprio(0);
  };

  stage(&Ks[0][0], &Vts[0][0], 0);
  __syncthreads();

#pragma unroll 1
  for (int t = 0; t < 15; ++t) {
    stage(&Ks[1][0], &Vts[1][0], 2 * t + 1);
    tile(&Ks[0][0], &Vts[0][0], 2 * t);
    __syncthreads();
    stage(&Ks[0][0], &Vts[0][0], 2 * t + 2);
    tile(&Ks[1][0], &Vts[1][0], 2 * t + 1);
    __syncthreads();
  }
  stage(&Ks[1][0], &Vts[1][0], 31);
  tile(&Ks[0][0], &Vts[0][0], 30);
  __syncthreads();
  tile(&Ks[1][0], &Vts[1][0], 31);

  // epilogue: acc_s[r] = softmax denom for q=crow(r,h1) — same layout as acc0/1
  const size_t obase = (size_t)(b * SLEN + q0);
#pragma unroll
  for (int r = 0; r < 16; ++r) {
    const int qr = (r & 3) + 8 * (r >> 2) + 4 * h1;
    const float si = 1.0f / acc_s[r];
    float* op = out + (obase + qr) * HDIM + h * DHEAD;
    op[l31]      = acc0[r] * si;
    op[32 + l31] = acc1[r] * si;
  }
}

extern "C" void kernel_launch(void* const* d_in, const int* in_sizes, int n_in,
                              void* d_out, int out_size, void* d_ws, size_t ws_size,
                              hipStream_t stream) {
  (void)in_sizes; (void)n_in; (void)out_size; (void)ws_size;
  const float* hs   = (const float*)d_in[0];
  const float* mask = (const float*)d_in[1];
  const float* Wq   = (const float*)d_in[2];
  const float* bq   = (const float*)d_in[3];
  const float* Wk   = (const float*)d_in[4];
  const float* bk   = (const float*)d_in[5];
  const float* Wv   = (const float*)d_in[6];
  const float* bv   = (const float*)d_in[7];
  float* out = (float*)d_out;

  char* ws = (char*)d_ws;
  const size_t MTOK = (size_t)BATCH * SLEN;  // 8192
  const size_t MB = 1024 * 1024;
  u16* HSb = (u16*)ws;                       // 16MB
  u16* Wqs = (u16*)(ws + 16 * MB);           // 2MB each (scaled)
  u16* Wks = (u16*)(ws + 18 * MB);
  u16* Wvs = (u16*)(ws + 20 * MB);
  u16* Qs  = (u16*)(ws + 22 * MB);           // 16MB scaled mixed_q
  u16* Kb  = (u16*)(ws + 38 * MB);           // 16MB
  u16* Vt  = (u16*)(ws + 54 * MB);           // 16MB transposed V
  float* m2  = (float*)(ws + 70 * MB);       // 32KB
  float* bqs = m2 + MTOK;                    // 4KB
  float* flg = bqs + 1024;                   // 16B

  prep_all<<<11298, 256, 0, stream>>>((const float4*)hs, (const float4*)Wq,
                                      (const float4*)Wk, (const float4*)Wv,
                                      mask, bq, HSb, Wqs, Wks, Wvs, m2, bqs, flg);

  dim3 gg(HDIM / 128, MTOK / 128);       // (8, 64)
  gemm_bt<<<gg, 256, 0, stream>>>(HSb, Wqs, bqs, Qs);
  dim3 gkv(HDIM / 128, MTOK / 128, 2);
  gemm_kv<<<gkv, 256, 0, stream>>>(Qs, Wks, bk, Kb, Wvs, bv, Vt);

  attn_kernel<<<BATCH * NHEAD * (SLEN / 128), 256, 0, stream>>>(Qs, Kb, Vt, m2,
                                                                flg, out);
}

// Round 10
// 172.231 us; speedup vs baseline: 1.0911x; 1.0911x over previous
//
#include <hip/hip_runtime.h>
#include <stdint.h>

typedef float  f32x4  __attribute__((ext_vector_type(4)));
typedef float  f32x16 __attribute__((ext_vector_type(16)));
typedef short  s16x8  __attribute__((ext_vector_type(8)));
typedef unsigned int u32x4 __attribute__((ext_vector_type(4)));
typedef unsigned short u16;
typedef u16    u16x4 __attribute__((ext_vector_type(4)));

#define SLEN 2048
#define HDIM 1024
#define NHEAD 16
#define DHEAD 64
#define BATCH 4
#define LOG2E 1.44269504088896340736f
#define SC2   0.18033688011111772f   /* 0.125 * log2(e) */
#define ISC2  5.5451774444795623f    /* 1/SC2 */

__device__ __forceinline__ u16 f2bf(float f) {
  uint32_t u = __builtin_bit_cast(uint32_t, f);
  u += 0x7FFFu + ((u >> 16) & 1u);
  return (u16)(u >> 16);
}

__device__ __forceinline__ uint32_t cvtpk2(float a, float b) {
  uint32_t r;
  asm("v_cvt_pk_bf16_f32 %0, %1, %2" : "=v"(r) : "v"(a), "v"(b));
  return r;
}

__device__ __forceinline__ void gld_lds16(const void* g, void* l) {
  __builtin_amdgcn_global_load_lds(
      (const __attribute__((address_space(1))) unsigned int*)g,
      (__attribute__((address_space(3))) unsigned int*)l, 16, 0, 0);
}

// ---- fused prep: HS->bf16, 3 weights scaled->bf16, m2, bqs, mask-zero flag ----
__global__ __launch_bounds__(256) void prep_all(
    const float4* __restrict__ hs, const float4* __restrict__ W0,
    const float4* __restrict__ W1, const float4* __restrict__ W2,
    const float* __restrict__ mask, const float* __restrict__ bq,
    u16* __restrict__ HSb, u16* __restrict__ O0, u16* __restrict__ O1,
    u16* __restrict__ O2, float* __restrict__ m2, float* __restrict__ bqs,
    float* __restrict__ flagp) {
  const int bid = blockIdx.x, tid = threadIdx.x;
  if (bid < 8192) {                       // hidden states: 8M elems
    int i = bid * 256 + tid;
    float4 v = hs[i];
    u16x4 o;
    o.x = f2bf(v.x); o.y = f2bf(v.y); o.z = f2bf(v.z); o.w = f2bf(v.w);
    *(u16x4*)(HSb + (size_t)i * 4) = o;
  } else if (bid < 11264) {               // 3 weight matrices
    int zz = (bid - 8192) >> 10;
    int i = ((bid - 8192) & 1023) * 256 + tid;
    const float4* in = zz == 0 ? W0 : (zz == 1 ? W1 : W2);
    u16* out = zz == 0 ? O0 : (zz == 1 ? O1 : O2);
    const float sc = zz == 0 ? SC2 : ISC2;
    float4 v = in[i];
    u16x4 o;
    o.x = f2bf(v.x * sc); o.y = f2bf(v.y * sc);
    o.z = f2bf(v.z * sc); o.w = f2bf(v.w * sc);
    *(u16x4*)(out + (size_t)i * 4) = o;
  } else if (bid < 11296) {               // m2 = mask*LOG2E (8192 floats)
    int i = (bid - 11264) * 256 + tid;
    m2[i] = mask[i] * LOG2E;
  } else if (bid < 11297) {               // bqs = bq*SC2 (1024 floats)
#pragma unroll
    for (int k = 0; k < 4; ++k) bqs[tid + k * 256] = bq[tid + k * 256] * SC2;
  } else {                                // mask nonzero flag (4 floats)
    float a = 0.f;
#pragma unroll
    for (int k = 0; k < 32; ++k) a += __builtin_fabsf(mask[tid + k * 256]);
    int nz = __any(a != 0.f) ? 1 : 0;
    if ((tid & 63) == 0) flagp[tid >> 6] = (float)nz;
  }
}

// ---------------- GEMM: C[M,1024] = A @ W^T + bias ----------------
// 128x128 tile, BK=32, 4-slot LDS ring, counted vmcnt(8) (no drains),
// one raw s_barrier per sub-tile, XOR chunk swizzle, XCD-chunked blocks.
// MODE 0: row-major C. MODE 1: transposed-V layout Vt[(s>>11)*1024+col][s&2047]
__device__ __forceinline__ void gemm_body(const u16* __restrict__ A,
                                          const u16* __restrict__ W,
                                          const float* __restrict__ bias,
                                          u16* __restrict__ C, int mode) {
  __shared__ u16 As[4][128 * 32];
  __shared__ u16 Bs[4][128 * 32];
  const int tid = threadIdx.x;
  const int lane = tid & 63;
  const int w = tid >> 6;
  const int wr = w >> 1, wc = w & 1;
  // XCD-chunked bijective swizzle of the 512-block (x,y) grid (gridDim.x==8)
  const int flat = blockIdx.x + blockIdx.y * 8;
  const int swz = (flat & 7) * 64 + (flat >> 3);
  const int brow = (swz >> 3) * 128;
  const int bcol = (swz & 7) * 128;
  const int l15 = lane & 15, l4 = lane >> 4;

  // staging: 512 16B-chunks per 128x32 sub-tile; thread t owns chunks t, t+256.
  // LDS[r][pc] holds global chunk pc ^ ((r>>1)&3)  (involution)
  const int r0 = tid >> 2, c0 = tid & 3;
  const int sc0 = c0 ^ ((r0 >> 1) & 3);
  const int r1 = r0 + 64;
  const int sc1 = c0 ^ ((r1 >> 1) & 3);
  const u16* Abase = A + (size_t)brow * HDIM;
  const u16* Bbase = W + (size_t)bcol * HDIM;

  f32x4 acc[4][4];
#pragma unroll
  for (int m = 0; m < 4; ++m)
#pragma unroll
    for (int n = 0; n < 4; ++n) acc[m][n] = f32x4{0.f, 0.f, 0.f, 0.f};

  auto stage = [&](int s) {
    const int slot = s & 3;
    const int k0 = s * 32;
    gld_lds16(Abase + (size_t)r0 * HDIM + k0 + sc0 * 8, &As[slot][tid * 8]);
    gld_lds16(Abase + (size_t)r1 * HDIM + k0 + sc1 * 8,
              &As[slot][(tid + 256) * 8]);
    gld_lds16(Bbase + (size_t)r0 * HDIM + k0 + sc0 * 8, &Bs[slot][tid * 8]);
    gld_lds16(Bbase + (size_t)r1 * HDIM + k0 + sc1 * 8,
              &Bs[slot][(tid + 256) * 8]);
  };

  auto compute = [&](int s) {
    const int slot = s & 3;
    s16x8 af[4], bf[4];
#pragma unroll
    for (int m = 0; m < 4; ++m) {
      const int row = wr * 64 + m * 16 + l15;
      const int pc = l4 ^ ((row >> 1) & 3);
      af[m] = *(const s16x8*)&As[slot][row * 32 + pc * 8];
    }
#pragma unroll
    for (int n = 0; n < 4; ++n) {
      const int row = wc * 64 + n * 16 + l15;
      const int pc = l4 ^ ((row >> 1) & 3);
      bf[n] = *(const s16x8*)&Bs[slot][row * 32 + pc * 8];
    }
    if (s < 29) stage(s + 3);   // slot (s+3)&3 == (s-1)&3: all reads of s-1
                                // completed before this iteration's barrier.
#pragma unroll
    for (int m = 0; m < 4; ++m)
#pragma unroll
      for (int n = 0; n < 4; ++n)
        acc[m][n] = __builtin_amdgcn_mfma_f32_16x16x32_bf16(af[m], bf[n],
                                                            acc[m][n], 0, 0, 0);
  };

  stage(0); stage(1); stage(2);   // 3 sub-tiles in flight (12 loads/thread)

#pragma unroll 1
  for (int s = 0; s < 30; ++s) {
    // own 4 loads of sub-tile s retired when <=8 outstanding (tiles s+1, s+2)
    asm volatile("s_waitcnt vmcnt(8)" ::: "memory");
    asm volatile("s_barrier" ::: "memory");   // whole tile s resident
    compute(s);
  }
  asm volatile("s_waitcnt vmcnt(4)" ::: "memory");
  asm volatile("s_barrier" ::: "memory");
  compute(30);
  asm volatile("s_waitcnt vmcnt(0)" ::: "memory");
  asm volatile("s_barrier" ::: "memory");
  compute(31);

#pragma unroll
  for (int n = 0; n < 4; ++n) {
    int col = bcol + wc * 64 + n * 16 + l15;
    float bv = bias[col];
#pragma unroll
    for (int m = 0; m < 4; ++m) {
      int row0 = brow + wr * 64 + m * 16 + l4 * 4;
      if (mode == 0) {
#pragma unroll
        for (int j = 0; j < 4; ++j)
          C[(size_t)(row0 + j) * HDIM + col] = f2bf(acc[m][n][j] + bv);
      } else {
        u16x4 o;
#pragma unroll
        for (int j = 0; j < 4; ++j) o[j] = f2bf(acc[m][n][j] + bv);
        *(u16x4*)(C + (size_t)(((row0 >> 11) << 10) + col) * SLEN +
                  (row0 & (SLEN - 1))) = o;
      }
    }
  }
}

__global__ __launch_bounds__(256) void gemm_bt(const u16* __restrict__ A,
                                               const u16* __restrict__ W,
                                               const float* __restrict__ bias,
                                               u16* __restrict__ C) {
  gemm_body(A, W, bias, C, 0);
}

__global__ __launch_bounds__(256) void gemm_kv(const u16* __restrict__ A,
                                               const u16* __restrict__ Wk,
                                               const float* __restrict__ bk,
                                               u16* __restrict__ K,
                                               const u16* __restrict__ Wv,
                                               const float* __restrict__ bv,
                                               u16* __restrict__ Vt) {
  if (blockIdx.z == 0) gemm_body(A, Wk, bk, K, 0);
  else                 gemm_body(A, Wv, bv, Vt, 1);
}

// ---------------- Flash attention v9 (unchanged from R9) ----------------
__global__ __launch_bounds__(256, 4) void attn_kernel(
    const u16* __restrict__ Qs, const u16* __restrict__ Kb,
    const u16* __restrict__ Vtg, const float* __restrict__ m2g,
    const float* __restrict__ flagp, float* __restrict__ out) {
  __shared__ u16 Ks[2][64 * 64];
  __shared__ u16 Vts[2][64 * 64];

  const int tid = threadIdx.x;
  const int lane = tid & 63;
  const int w = tid >> 6;          // 0..3
  const int bid = blockIdx.x;
  const int swz = (bid & 7) * 128 + (bid >> 3);
  const int qt = swz & 15;
  const int bh = swz >> 4;
  const int b = bh >> 4, h = bh & 15;
  const int l31 = lane & 31;
  const int h1 = lane >> 5;        // 0/1

  const float4 fl = *(const float4*)flagp;
  const bool mz = (fl.x == 0.f && fl.y == 0.f && fl.z == 0.f && fl.w == 0.f);

  const int q0 = qt * 128 + w * 32;
  s16x8 qf[4];
  {
    const u16* qp = Qs + (size_t)(b * SLEN + q0 + l31) * HDIM + h * DHEAD + h1 * 8;
#pragma unroll
    for (int dch = 0; dch < 4; ++dch) qf[dch] = *(const s16x8*)(qp + dch * 16);
  }

  const s16x8 onesf = {(short)0x3F80, (short)0x3F80, (short)0x3F80,
                       (short)0x3F80, (short)0x3F80, (short)0x3F80,
                       (short)0x3F80, (short)0x3F80};

  const float zf = fl.x * 0.0f;
  f32x16 zc;
#pragma unroll
  for (int i = 0; i < 16; ++i) zc[i] = zf;

  const int r0 = tid >> 3, c0 = tid & 7;
  const int cl0 = c0 ^ (r0 & 7);
  const int r1 = r0 + 32;
  const int cl1 = c0 ^ (r1 & 7);
  const u16* Kbase = Kb + (size_t)(b * SLEN) * HDIM + h * DHEAD;
  const u16* Vbase = Vtg + (size_t)bh * 64 * SLEN;
  const float* mbase = m2g + b * SLEN;
  const u16* KstA = Kbase + (size_t)r0 * HDIM + cl0 * 8;
  const u16* KstB = Kbase + (size_t)r1 * HDIM + cl1 * 8;
  const u16* VstA = Vbase + (size_t)r0 * SLEN + cl0 * 8;
  const u16* VstB = Vbase + (size_t)r1 * SLEN + cl1 * 8;

  f32x16 acc0{}, acc1{}, acc_s{};

  auto stage = [&](u16* Kd, u16* Vd, int kbn) {
    const size_t ko = (size_t)kbn * 64 * HDIM;
    const int vo = kbn * 64;
    gld_lds16(KstA + ko, Kd + tid * 8);
    gld_lds16(KstB + ko, Kd + (tid + 256) * 8);
    gld_lds16(VstA + vo, Vd + tid * 8);
    gld_lds16(VstB + vo, Vd + (tid + 256) * 8);
  };

  auto tile = [&](const u16* Kc, const u16* Vc, int kb) {
    uint32_t W[16];
#pragma unroll
    for (int kblk = 0; kblk < 2; ++kblk) {
      f32x16 cinit;
      if (mz) {
        cinit = zc;
      } else {
#pragma unroll
        for (int g = 0; g < 4; ++g) {
          float4 mk =
              *(const float4*)(mbase + kb * 64 + kblk * 32 + g * 8 + h1 * 4);
          cinit[4 * g + 0] = mk.x; cinit[4 * g + 1] = mk.y;
          cinit[4 * g + 2] = mk.z; cinit[4 * g + 3] = mk.w;
        }
      }
      const int row = kblk * 32 + l31;
      __builtin_amdgcn_s_setprio(1);
      f32x16 sT;
      {
        const int ch = h1 ^ (row & 7);
        s16x8 kf = *(const s16x8*)(Kc + row * 64 + ch * 8);
        sT = __builtin_amdgcn_mfma_f32_32x32x16_bf16(kf, qf[0], cinit, 0, 0, 0);
      }
#pragma unroll
      for (int dch = 1; dch < 4; ++dch) {
        const int ch = (dch * 2 + h1) ^ (row & 7);
        s16x8 kf = *(const s16x8*)(Kc + row * 64 + ch * 8);
        sT = __builtin_amdgcn_mfma_f32_32x32x16_bf16(kf, qf[dch], sT, 0, 0, 0);
      }
      __builtin_amdgcn_s_setprio(0);
#pragma unroll
      for (int g = 0; g < 4; ++g) {
        float p0 = __builtin_amdgcn_exp2f(sT[4 * g + 0]);
        float p1 = __builtin_amdgcn_exp2f(sT[4 * g + 1]);
        float p2 = __builtin_amdgcn_exp2f(sT[4 * g + 2]);
        float p3 = __builtin_amdgcn_exp2f(sT[4 * g + 3]);
        W[kblk * 8 + 2 * g]     = cvtpk2(p0, p1);
        W[kblk * 8 + 2 * g + 1] = cvtpk2(p2, p3);
      }
    }

#pragma unroll
    for (int c = 0; c < 4; ++c) {
#pragma unroll
      for (int e = 0; e < 2; ++e) {
        uint32_t a = W[4 * c + e], bb = W[4 * c + 2 + e];
        asm("v_permlane32_swap_b32 %0, %1" : "+v"(a), "+v"(bb));
        W[4 * c + e] = a;
        W[4 * c + 2 + e] = bb;
      }
    }

    __builtin_amdgcn_s_setprio(1);
#pragma unroll
    for (int c = 0; c < 4; ++c) {
      u32x4 t = {W[4 * c], W[4 * c + 1], W[4 * c + 2], W[4 * c + 3]};
      s16x8 af = __builtin_bit_cast(s16x8, t);
      const int ch = (c * 2 + h1) ^ (l31 & 7);
      s16x8 vf0 = *(const s16x8*)(Vc + l31 * 64 + ch * 8);
      s16x8 vf1 = *(const s16x8*)(Vc + (32 + l31) * 64 + ch * 8);
      acc0 = __builtin_amdgcn_mfma_f32_32x32x16_bf16(af, vf0, acc0, 0, 0, 0);
      acc1 = __builtin_amdgcn_mfma_f32_32x32x16_bf16(af, vf1, acc1, 0, 0, 0);
      acc_s = __builtin_amdgcn_mfma_f32_32x32x16_bf16(af, onesf, acc_s, 0, 0, 0);
    }
    __builtin_amdgcn_s_setprio(0);
  };

  stage(&Ks[0][0], &Vts[0][0], 0);
  __syncthreads();

#pragma unroll 1
  for (int t = 0; t < 15; ++t) {
    stage(&Ks[1][0], &Vts[1][0], 2 * t + 1);
    tile(&Ks[0][0], &Vts[0][0], 2 * t);
    __syncthreads();
    stage(&Ks[0][0], &Vts[0][0], 2 * t + 2);
    tile(&Ks[1][0], &Vts[1][0], 2 * t + 1);
    __syncthreads();
  }
  stage(&Ks[1][0], &Vts[1][0], 31);
  tile(&Ks[0][0], &Vts[0][0], 30);
  __syncthreads();
  tile(&Ks[1][0], &Vts[1][0], 31);

  const size_t obase = (size_t)(b * SLEN + q0);
#pragma unroll
  for (int r = 0; r < 16; ++r) {
    const int qr = (r & 3) + 8 * (r >> 2) + 4 * h1;
    const float si = 1.0f / acc_s[r];
    float* op = out + (obase + qr) * HDIM + h * DHEAD;
    op[l31]      = acc0[r] * si;
    op[32 + l31] = acc1[r] * si;
  }
}

extern "C" void kernel_launch(void* const* d_in, const int* in_sizes, int n_in,
                              void* d_out, int out_size, void* d_ws, size_t ws_size,
                              hipStream_t stream) {
  (void)in_sizes; (void)n_in; (void)out_size; (void)ws_size;
  const float* hs   = (const float*)d_in[0];
  const float* mask = (const float*)d_in[1];
  const float* Wq   = (const float*)d_in[2];
  const float* bq   = (const float*)d_in[3];
  const float* Wk   = (const float*)d_in[4];
  const float* bk   = (const float*)d_in[5];
  const float* Wv   = (const float*)d_in[6];
  const float* bv   = (const float*)d_in[7];
  float* out = (float*)d_out;

  char* ws = (char*)d_ws;
  const size_t MTOK = (size_t)BATCH * SLEN;  // 8192
  const size_t MB = 1024 * 1024;
  u16* HSb = (u16*)ws;                       // 16MB
  u16* Wqs = (u16*)(ws + 16 * MB);           // 2MB each (scaled)
  u16* Wks = (u16*)(ws + 18 * MB);
  u16* Wvs = (u16*)(ws + 20 * MB);
  u16* Qs  = (u16*)(ws + 22 * MB);           // 16MB scaled mixed_q
  u16* Kb  = (u16*)(ws + 38 * MB);           // 16MB
  u16* Vt  = (u16*)(ws + 54 * MB);           // 16MB transposed V
  float* m2  = (float*)(ws + 70 * MB);       // 32KB
  float* bqs = m2 + MTOK;                    // 4KB
  float* flg = bqs + 1024;                   // 16B

  prep_all<<<11298, 256, 0, stream>>>((const float4*)hs, (const float4*)Wq,
                                      (const float4*)Wk, (const float4*)Wv,
                                      mask, bq, HSb, Wqs, Wks, Wvs, m2, bqs, flg);

  dim3 gg(HDIM / 128, MTOK / 128);       // (8, 64)
  gemm_bt<<<gg, 256, 0, stream>>>(HSb, Wqs, bqs, Qs);
  dim3 gkv(HDIM / 128, MTOK / 128, 2);
  gemm_kv<<<gkv, 256, 0, stream>>>(Qs, Wks, bk, Kb, Wvs, bv, Vt);

  attn_kernel<<<BATCH * NHEAD * (SLEN / 128), 256, 0, stream>>>(Qs, Kb, Vt, m2,
                                                                flg, out);
}

// Round 11
// 166.474 us; speedup vs baseline: 1.1288x; 1.0346x over previous
//
#include <hip/hip_runtime.h>
#include <stdint.h>

typedef float  f32x4  __attribute__((ext_vector_type(4)));
typedef float  f32x16 __attribute__((ext_vector_type(16)));
typedef short  s16x8  __attribute__((ext_vector_type(8)));
typedef unsigned int u32x4 __attribute__((ext_vector_type(4)));
typedef unsigned short u16;
typedef u16    u16x4 __attribute__((ext_vector_type(4)));

#define SLEN 2048
#define HDIM 1024
#define NHEAD 16
#define DHEAD 64
#define BATCH 4
#define LOG2E 1.44269504088896340736f
#define SC2   0.18033688011111772f   /* 0.125 * log2(e) */
#define ISC2  5.5451774444795623f    /* 1/SC2 */

__device__ __forceinline__ u16 f2bf(float f) {
  uint32_t u = __builtin_bit_cast(uint32_t, f);
  u += 0x7FFFu + ((u >> 16) & 1u);
  return (u16)(u >> 16);
}

__device__ __forceinline__ uint32_t cvtpk2(float a, float b) {
  uint32_t r;
  asm("v_cvt_pk_bf16_f32 %0, %1, %2" : "=v"(r) : "v"(a), "v"(b));
  return r;
}

__device__ __forceinline__ void gld_lds16(const void* g, void* l) {
  __builtin_amdgcn_global_load_lds(
      (const __attribute__((address_space(1))) unsigned int*)g,
      (__attribute__((address_space(3))) unsigned int*)l, 16, 0, 0);
}

// ---- fused prep: HS->bf16, 3 weights scaled->bf16, m2, bqs, mask-zero flag ----
__global__ __launch_bounds__(256) void prep_all(
    const float4* __restrict__ hs, const float4* __restrict__ W0,
    const float4* __restrict__ W1, const float4* __restrict__ W2,
    const float* __restrict__ mask, const float* __restrict__ bq,
    u16* __restrict__ HSb, u16* __restrict__ O0, u16* __restrict__ O1,
    u16* __restrict__ O2, float* __restrict__ m2, float* __restrict__ bqs,
    float* __restrict__ flagp) {
  const int bid = blockIdx.x, tid = threadIdx.x;
  if (bid < 8192) {                       // hidden states: 8M elems
    int i = bid * 256 + tid;
    float4 v = hs[i];
    u16x4 o;
    o.x = f2bf(v.x); o.y = f2bf(v.y); o.z = f2bf(v.z); o.w = f2bf(v.w);
    *(u16x4*)(HSb + (size_t)i * 4) = o;
  } else if (bid < 11264) {               // 3 weight matrices
    int zz = (bid - 8192) >> 10;
    int i = ((bid - 8192) & 1023) * 256 + tid;
    const float4* in = zz == 0 ? W0 : (zz == 1 ? W1 : W2);
    u16* out = zz == 0 ? O0 : (zz == 1 ? O1 : O2);
    const float sc = zz == 0 ? SC2 : ISC2;
    float4 v = in[i];
    u16x4 o;
    o.x = f2bf(v.x * sc); o.y = f2bf(v.y * sc);
    o.z = f2bf(v.z * sc); o.w = f2bf(v.w * sc);
    *(u16x4*)(out + (size_t)i * 4) = o;
  } else if (bid < 11296) {               // m2 = mask*LOG2E (8192 floats)
    int i = (bid - 11264) * 256 + tid;
    m2[i] = mask[i] * LOG2E;
  } else if (bid < 11297) {               // bqs = bq*SC2 (1024 floats)
#pragma unroll
    for (int k = 0; k < 4; ++k) bqs[tid + k * 256] = bq[tid + k * 256] * SC2;
  } else {                                // mask nonzero flag (4 floats)
    float a = 0.f;
#pragma unroll
    for (int k = 0; k < 32; ++k) a += __builtin_fabsf(mask[tid + k * 256]);
    int nz = __any(a != 0.f) ? 1 : 0;
    if ((tid & 63) == 0) flagp[tid >> 6] = (float)nz;
  }
}

// ---------------- GEMM: C[M,1024] = A @ W^T + bias ----------------
// 128x128 tile, BK=32, 4-slot LDS ring, counted vmcnt(8) (no drains),
// one raw s_barrier per sub-tile, XOR chunk swizzle, XCD-chunked blocks.
// MODE 0: row-major C. MODE 1: transposed-V layout Vt[(s>>11)*1024+col][s&2047]
__device__ __forceinline__ void gemm_body(const u16* __restrict__ A,
                                          const u16* __restrict__ W,
                                          const float* __restrict__ bias,
                                          u16* __restrict__ C, int mode) {
  __shared__ u16 As[4][128 * 32];
  __shared__ u16 Bs[4][128 * 32];
  const int tid = threadIdx.x;
  const int lane = tid & 63;
  const int w = tid >> 6;
  const int wr = w >> 1, wc = w & 1;
  // XCD-chunked bijective swizzle of the 512-block (x,y) grid (gridDim.x==8)
  const int flat = blockIdx.x + blockIdx.y * 8;
  const int swz = (flat & 7) * 64 + (flat >> 3);
  const int brow = (swz >> 3) * 128;
  const int bcol = (swz & 7) * 128;
  const int l15 = lane & 15, l4 = lane >> 4;

  // staging: 512 16B-chunks per 128x32 sub-tile; thread t owns chunks t, t+256.
  // LDS[r][pc] holds global chunk pc ^ ((r>>1)&3)  (involution)
  const int r0 = tid >> 2, c0 = tid & 3;
  const int sc0 = c0 ^ ((r0 >> 1) & 3);
  const int r1 = r0 + 64;
  const int sc1 = c0 ^ ((r1 >> 1) & 3);
  const u16* Abase = A + (size_t)brow * HDIM;
  const u16* Bbase = W + (size_t)bcol * HDIM;

  f32x4 acc[4][4];
#pragma unroll
  for (int m = 0; m < 4; ++m)
#pragma unroll
    for (int n = 0; n < 4; ++n) acc[m][n] = f32x4{0.f, 0.f, 0.f, 0.f};

  auto stage = [&](int s) {
    const int slot = s & 3;
    const int k0 = s * 32;
    gld_lds16(Abase + (size_t)r0 * HDIM + k0 + sc0 * 8, &As[slot][tid * 8]);
    gld_lds16(Abase + (size_t)r1 * HDIM + k0 + sc1 * 8,
              &As[slot][(tid + 256) * 8]);
    gld_lds16(Bbase + (size_t)r0 * HDIM + k0 + sc0 * 8, &Bs[slot][tid * 8]);
    gld_lds16(Bbase + (size_t)r1 * HDIM + k0 + sc1 * 8,
              &Bs[slot][(tid + 256) * 8]);
  };

  auto compute = [&](int s) {
    const int slot = s & 3;
    s16x8 af[4], bf[4];
#pragma unroll
    for (int m = 0; m < 4; ++m) {
      const int row = wr * 64 + m * 16 + l15;
      const int pc = l4 ^ ((row >> 1) & 3);
      af[m] = *(const s16x8*)&As[slot][row * 32 + pc * 8];
    }
#pragma unroll
    for (int n = 0; n < 4; ++n) {
      const int row = wc * 64 + n * 16 + l15;
      const int pc = l4 ^ ((row >> 1) & 3);
      bf[n] = *(const s16x8*)&Bs[slot][row * 32 + pc * 8];
    }
    if (s < 29) stage(s + 3);   // slot (s+3)&3 == (s-1)&3: all reads of s-1
                                // completed before this iteration's barrier.
#pragma unroll
    for (int m = 0; m < 4; ++m)
#pragma unroll
      for (int n = 0; n < 4; ++n)
        acc[m][n] = __builtin_amdgcn_mfma_f32_16x16x32_bf16(af[m], bf[n],
                                                            acc[m][n], 0, 0, 0);
  };

  stage(0); stage(1); stage(2);   // 3 sub-tiles in flight (12 loads/thread)

#pragma unroll 1
  for (int s = 0; s < 30; ++s) {
    // own 4 loads of sub-tile s retired when <=8 outstanding (tiles s+1, s+2)
    asm volatile("s_waitcnt vmcnt(8)" ::: "memory");
    asm volatile("s_barrier" ::: "memory");   // whole tile s resident
    compute(s);
  }
  asm volatile("s_waitcnt vmcnt(4)" ::: "memory");
  asm volatile("s_barrier" ::: "memory");
  compute(30);
  asm volatile("s_waitcnt vmcnt(0)" ::: "memory");
  asm volatile("s_barrier" ::: "memory");
  compute(31);

#pragma unroll
  for (int n = 0; n < 4; ++n) {
    int col = bcol + wc * 64 + n * 16 + l15;
    float bv = bias[col];
#pragma unroll
    for (int m = 0; m < 4; ++m) {
      int row0 = brow + wr * 64 + m * 16 + l4 * 4;
      if (mode == 0) {
#pragma unroll
        for (int j = 0; j < 4; ++j)
          C[(size_t)(row0 + j) * HDIM + col] = f2bf(acc[m][n][j] + bv);
      } else {
        u16x4 o;
#pragma unroll
        for (int j = 0; j < 4; ++j) o[j] = f2bf(acc[m][n][j] + bv);
        *(u16x4*)(C + (size_t)(((row0 >> 11) << 10) + col) * SLEN +
                  (row0 & (SLEN - 1))) = o;
      }
    }
  }
}

__global__ __launch_bounds__(256) void gemm_bt(const u16* __restrict__ A,
                                               const u16* __restrict__ W,
                                               const float* __restrict__ bias,
                                               u16* __restrict__ C) {
  gemm_body(A, W, bias, C, 0);
}

__global__ __launch_bounds__(256) void gemm_kv(const u16* __restrict__ A,
                                               const u16* __restrict__ Wk,
                                               const float* __restrict__ bk,
                                               u16* __restrict__ K,
                                               const u16* __restrict__ Wv,
                                               const float* __restrict__ bv,
                                               u16* __restrict__ Vt) {
  if (blockIdx.z == 0) gemm_body(A, Wk, bk, K, 0);
  else                 gemm_body(A, Wv, bv, Vt, 1);
}

// ---------------- Flash attention v10: 8 waves, QBLK=256 ----------------
// 512 thr / 8 waves, wave owns 32 q-rows. Staging per tile: 1 K + 1 V chunk
// per thread (half the R9 staging traffic). Same 32x32 MFMA in-register-P
// softmax with MFMA row-sum.
__global__ __launch_bounds__(512, 4) void attn_kernel(
    const u16* __restrict__ Qs, const u16* __restrict__ Kb,
    const u16* __restrict__ Vtg, const float* __restrict__ m2g,
    const float* __restrict__ flagp, float* __restrict__ out) {
  __shared__ u16 Ks[2][64 * 64];
  __shared__ u16 Vts[2][64 * 64];

  const int tid = threadIdx.x;
  const int lane = tid & 63;
  const int w = tid >> 6;          // 0..7
  // XCD-chunked bijective swizzle (512 blocks, 64 per XCD; 8 bh per XCD)
  const int bid = blockIdx.x;
  const int swz = (bid & 7) * 64 + (bid >> 3);
  const int qt = swz & 7;          // 2048/256 q-tiles
  const int bh = swz >> 3;
  const int b = bh >> 4, h = bh & 15;
  const int l31 = lane & 31;
  const int h1 = lane >> 5;        // 0/1

  const float4 fl = *(const float4*)flagp;
  const bool mz = (fl.x == 0.f && fl.y == 0.f && fl.z == 0.f && fl.w == 0.f);

  // Q fragments (B-operand): lane holds Q[q0+l31][dch*16 + h1*8 .. +8]
  const int q0 = qt * 256 + w * 32;
  s16x8 qf[4];
  {
    const u16* qp = Qs + (size_t)(b * SLEN + q0 + l31) * HDIM + h * DHEAD + h1 * 8;
#pragma unroll
    for (int dch = 0; dch < 4; ++dch) qf[dch] = *(const s16x8*)(qp + dch * 16);
  }

  const s16x8 onesf = {(short)0x3F80, (short)0x3F80, (short)0x3F80,
                       (short)0x3F80, (short)0x3F80, (short)0x3F80,
                       (short)0x3F80, (short)0x3F80};

  const float zf = fl.x * 0.0f;
  f32x16 zc;
#pragma unroll
  for (int i = 0; i < 16; ++i) zc[i] = zf;

  // staging: 512 16B-chunks per 64x64 tile, ONE per thread for each of K, V
  const int r0 = tid >> 3, c0 = tid & 7;
  const int cl0 = c0 ^ (r0 & 7);
  const u16* Kbase = Kb + (size_t)(b * SLEN) * HDIM + h * DHEAD;
  const u16* Vbase = Vtg + (size_t)bh * 64 * SLEN;
  const float* mbase = m2g + b * SLEN;
  const u16* KstA = Kbase + (size_t)r0 * HDIM + cl0 * 8;
  const u16* VstA = Vbase + (size_t)r0 * SLEN + cl0 * 8;

  f32x16 acc0{}, acc1{}, acc_s{};

  auto stage = [&](u16* Kd, u16* Vd, int kbn) {
    const size_t ko = (size_t)kbn * 64 * HDIM;
    const int vo = kbn * 64;
    gld_lds16(KstA + ko, Kd + tid * 8);
    gld_lds16(VstA + vo, Vd + tid * 8);
  };

  auto tile = [&](const u16* Kc, const u16* Vc, int kb) {
    uint32_t W[16];
#pragma unroll
    for (int kblk = 0; kblk < 2; ++kblk) {
      f32x16 cinit;
      if (mz) {
        cinit = zc;
      } else {
#pragma unroll
        for (int g = 0; g < 4; ++g) {
          float4 mk =
              *(const float4*)(mbase + kb * 64 + kblk * 32 + g * 8 + h1 * 4);
          cinit[4 * g + 0] = mk.x; cinit[4 * g + 1] = mk.y;
          cinit[4 * g + 2] = mk.z; cinit[4 * g + 3] = mk.w;
        }
      }
      const int row = kblk * 32 + l31;
      __builtin_amdgcn_s_setprio(1);
      f32x16 sT;
      {
        const int ch = h1 ^ (row & 7);
        s16x8 kf = *(const s16x8*)(Kc + row * 64 + ch * 8);
        sT = __builtin_amdgcn_mfma_f32_32x32x16_bf16(kf, qf[0], cinit, 0, 0, 0);
      }
#pragma unroll
      for (int dch = 1; dch < 4; ++dch) {
        const int ch = (dch * 2 + h1) ^ (row & 7);
        s16x8 kf = *(const s16x8*)(Kc + row * 64 + ch * 8);
        sT = __builtin_amdgcn_mfma_f32_32x32x16_bf16(kf, qf[dch], sT, 0, 0, 0);
      }
      __builtin_amdgcn_s_setprio(0);
      // lane holds S^T[k][q=l31] (log2 domain, mask included)
#pragma unroll
      for (int g = 0; g < 4; ++g) {
        float p0 = __builtin_amdgcn_exp2f(sT[4 * g + 0]);
        float p1 = __builtin_amdgcn_exp2f(sT[4 * g + 1]);
        float p2 = __builtin_amdgcn_exp2f(sT[4 * g + 2]);
        float p3 = __builtin_amdgcn_exp2f(sT[4 * g + 3]);
        W[kblk * 8 + 2 * g]     = cvtpk2(p0, p1);
        W[kblk * 8 + 2 * g + 1] = cvtpk2(p2, p3);
      }
    }

    // half-exchange across lane-32 boundary: one v_permlane32_swap_b32 per pair
#pragma unroll
    for (int c = 0; c < 4; ++c) {
#pragma unroll
      for (int e = 0; e < 2; ++e) {
        uint32_t a = W[4 * c + e], bb = W[4 * c + 2 + e];
        asm("v_permlane32_swap_b32 %0, %1" : "+v"(a), "+v"(bb));
        W[4 * c + e] = a;
        W[4 * c + 2 + e] = bb;
      }
    }

    // PV + row-sum: acc[db] += P-frag(c) x V-frag(db,c); acc_s += P-frag x ones
    __builtin_amdgcn_s_setprio(1);
#pragma unroll
    for (int c = 0; c < 4; ++c) {
      u32x4 t = {W[4 * c], W[4 * c + 1], W[4 * c + 2], W[4 * c + 3]};
      s16x8 af = __builtin_bit_cast(s16x8, t);
      const int ch = (c * 2 + h1) ^ (l31 & 7);
      s16x8 vf0 = *(const s16x8*)(Vc + l31 * 64 + ch * 8);
      s16x8 vf1 = *(const s16x8*)(Vc + (32 + l31) * 64 + ch * 8);
      acc0 = __builtin_amdgcn_mfma_f32_32x32x16_bf16(af, vf0, acc0, 0, 0, 0);
      acc1 = __builtin_amdgcn_mfma_f32_32x32x16_bf16(af, vf1, acc1, 0, 0, 0);
      acc_s = __builtin_amdgcn_mfma_f32_32x32x16_bf16(af, onesf, acc_s, 0, 0, 0);
    }
    __builtin_amdgcn_s_setprio(0);
  };

  stage(&Ks[0][0], &Vts[0][0], 0);
  __syncthreads();

#pragma unroll 1
  for (int t = 0; t < 15; ++t) {
    stage(&Ks[1][0], &Vts[1][0], 2 * t + 1);
    tile(&Ks[0][0], &Vts[0][0], 2 * t);
    __syncthreads();
    stage(&Ks[0][0], &Vts[0][0], 2 * t + 2);
    tile(&Ks[1][0], &Vts[1][0], 2 * t + 1);
    __syncthreads();
  }
  stage(&Ks[1][0], &Vts[1][0], 31);
  tile(&Ks[0][0], &Vts[0][0], 30);
  __syncthreads();
  tile(&Ks[1][0], &Vts[1][0], 31);

  // epilogue: acc_s[r] = softmax denom for q=crow(r,h1) — same layout as acc0/1
  const size_t obase = (size_t)(b * SLEN + q0);
#pragma unroll
  for (int r = 0; r < 16; ++r) {
    const int qr = (r & 3) + 8 * (r >> 2) + 4 * h1;
    const float si = 1.0f / acc_s[r];
    float* op = out + (obase + qr) * HDIM + h * DHEAD;
    op[l31]      = acc0[r] * si;
    op[32 + l31] = acc1[r] * si;
  }
}

extern "C" void kernel_launch(void* const* d_in, const int* in_sizes, int n_in,
                              void* d_out, int out_size, void* d_ws, size_t ws_size,
                              hipStream_t stream) {
  (void)in_sizes; (void)n_in; (void)out_size; (void)ws_size;
  const float* hs   = (const float*)d_in[0];
  const float* mask = (const float*)d_in[1];
  const float* Wq   = (const float*)d_in[2];
  const float* bq   = (const float*)d_in[3];
  const float* Wk   = (const float*)d_in[4];
  const float* bk   = (const float*)d_in[5];
  const float* Wv   = (const float*)d_in[6];
  const float* bv   = (const float*)d_in[7];
  float* out = (float*)d_out;

  char* ws = (char*)d_ws;
  const size_t MTOK = (size_t)BATCH * SLEN;  // 8192
  const size_t MB = 1024 * 1024;
  u16* HSb = (u16*)ws;                       // 16MB
  u16* Wqs = (u16*)(ws + 16 * MB);           // 2MB each (scaled)
  u16* Wks = (u16*)(ws + 18 * MB);
  u16* Wvs = (u16*)(ws + 20 * MB);
  u16* Qs  = (u16*)(ws + 22 * MB);           // 16MB scaled mixed_q
  u16* Kb  = (u16*)(ws + 38 * MB);           // 16MB
  u16* Vt  = (u16*)(ws + 54 * MB);           // 16MB transposed V
  float* m2  = (float*)(ws + 70 * MB);       // 32KB
  float* bqs = m2 + MTOK;                    // 4KB
  float* flg = bqs + 1024;                   // 16B

  prep_all<<<11298, 256, 0, stream>>>((const float4*)hs, (const float4*)Wq,
                                      (const float4*)Wk, (const float4*)Wv,
                                      mask, bq, HSb, Wqs, Wks, Wvs, m2, bqs, flg);

  dim3 gg(HDIM / 128, MTOK / 128);       // (8, 64)
  gemm_bt<<<gg, 256, 0, stream>>>(HSb, Wqs, bqs, Qs);
  dim3 gkv(HDIM / 128, MTOK / 128, 2);
  gemm_kv<<<gkv, 256, 0, stream>>>(Qs, Wks, bk, Kb, Wvs, bv, Vt);

  attn_kernel<<<BATCH * NHEAD * (SLEN / 256), 512, 0, stream>>>(Qs, Kb, Vt, m2,
                                                                flg, out);
}

// Round 12
// 164.604 us; speedup vs baseline: 1.1417x; 1.0114x over previous
//
#include <hip/hip_runtime.h>
#include <stdint.h>

typedef float  f32x4  __attribute__((ext_vector_type(4)));
typedef float  f32x16 __attribute__((ext_vector_type(16)));
typedef short  s16x8  __attribute__((ext_vector_type(8)));
typedef unsigned int u32x4 __attribute__((ext_vector_type(4)));
typedef unsigned short u16;
typedef u16    u16x4 __attribute__((ext_vector_type(4)));

#define SLEN 2048
#define HDIM 1024
#define NHEAD 16
#define DHEAD 64
#define BATCH 4
#define LOG2E 1.44269504088896340736f
#define SC2   0.18033688011111772f   /* 0.125 * log2(e) */
#define ISC2  5.5451774444795623f    /* 1/SC2 */

__device__ __forceinline__ u16 f2bf(float f) {
  uint32_t u = __builtin_bit_cast(uint32_t, f);
  u += 0x7FFFu + ((u >> 16) & 1u);
  return (u16)(u >> 16);
}

__device__ __forceinline__ uint32_t cvtpk2(float a, float b) {
  uint32_t r;
  asm("v_cvt_pk_bf16_f32 %0, %1, %2" : "=v"(r) : "v"(a), "v"(b));
  return r;
}

__device__ __forceinline__ void gld_lds16(const void* g, void* l) {
  __builtin_amdgcn_global_load_lds(
      (const __attribute__((address_space(1))) unsigned int*)g,
      (__attribute__((address_space(3))) unsigned int*)l, 16, 0, 0);
}

// ---- fused prep: HS->bf16, 3 weights scaled->bf16, m2, bqs, mask-zero flag ----
__global__ __launch_bounds__(256) void prep_all(
    const float4* __restrict__ hs, const float4* __restrict__ W0,
    const float4* __restrict__ W1, const float4* __restrict__ W2,
    const float* __restrict__ mask, const float* __restrict__ bq,
    u16* __restrict__ HSb, u16* __restrict__ O0, u16* __restrict__ O1,
    u16* __restrict__ O2, float* __restrict__ m2, float* __restrict__ bqs,
    float* __restrict__ flagp) {
  const int bid = blockIdx.x, tid = threadIdx.x;
  if (bid < 8192) {                       // hidden states: 8M elems
    int i = bid * 256 + tid;
    float4 v = hs[i];
    u16x4 o;
    o.x = f2bf(v.x); o.y = f2bf(v.y); o.z = f2bf(v.z); o.w = f2bf(v.w);
    *(u16x4*)(HSb + (size_t)i * 4) = o;
  } else if (bid < 11264) {               // 3 weight matrices
    int zz = (bid - 8192) >> 10;
    int i = ((bid - 8192) & 1023) * 256 + tid;
    const float4* in = zz == 0 ? W0 : (zz == 1 ? W1 : W2);
    u16* out = zz == 0 ? O0 : (zz == 1 ? O1 : O2);
    const float sc = zz == 0 ? SC2 : ISC2;
    float4 v = in[i];
    u16x4 o;
    o.x = f2bf(v.x * sc); o.y = f2bf(v.y * sc);
    o.z = f2bf(v.z * sc); o.w = f2bf(v.w * sc);
    *(u16x4*)(out + (size_t)i * 4) = o;
  } else if (bid < 11296) {               // m2 = mask*LOG2E (8192 floats)
    int i = (bid - 11264) * 256 + tid;
    m2[i] = mask[i] * LOG2E;
  } else if (bid < 11297) {               // bqs = bq*SC2 (1024 floats)
#pragma unroll
    for (int k = 0; k < 4; ++k) bqs[tid + k * 256] = bq[tid + k * 256] * SC2;
  } else {                                // mask nonzero flag (4 floats)
    float a = 0.f;
#pragma unroll
    for (int k = 0; k < 32; ++k) a += __builtin_fabsf(mask[tid + k * 256]);
    int nz = __any(a != 0.f) ? 1 : 0;
    if ((tid & 63) == 0) flagp[tid >> 6] = (float)nz;
  }
}

// ---------------- GEMM: C[M,1024] = A @ W^T + bias ----------------
// 128x128 tile, BK=32, 4-slot LDS ring, counted vmcnt(8) (no drains),
// one raw s_barrier per sub-tile, XOR chunk swizzle, XCD-chunked blocks.
// MODE 0: row-major C. MODE 1: transposed-V layout Vt[(s>>11)*1024+col][s&2047]
__device__ __forceinline__ void gemm_body(const u16* __restrict__ A,
                                          const u16* __restrict__ W,
                                          const float* __restrict__ bias,
                                          u16* __restrict__ C, int mode) {
  __shared__ u16 As[4][128 * 32];
  __shared__ u16 Bs[4][128 * 32];
  const int tid = threadIdx.x;
  const int lane = tid & 63;
  const int w = tid >> 6;
  const int wr = w >> 1, wc = w & 1;
  // XCD-chunked bijective swizzle of the 512-block (x,y) grid (gridDim.x==8)
  const int flat = blockIdx.x + blockIdx.y * 8;
  const int swz = (flat & 7) * 64 + (flat >> 3);
  const int brow = (swz >> 3) * 128;
  const int bcol = (swz & 7) * 128;
  const int l15 = lane & 15, l4 = lane >> 4;

  const int r0 = tid >> 2, c0 = tid & 3;
  const int sc0 = c0 ^ ((r0 >> 1) & 3);
  const int r1 = r0 + 64;
  const int sc1 = c0 ^ ((r1 >> 1) & 3);
  const u16* Abase = A + (size_t)brow * HDIM;
  const u16* Bbase = W + (size_t)bcol * HDIM;

  f32x4 acc[4][4];
#pragma unroll
  for (int m = 0; m < 4; ++m)
#pragma unroll
    for (int n = 0; n < 4; ++n) acc[m][n] = f32x4{0.f, 0.f, 0.f, 0.f};

  auto stage = [&](int s) {
    const int slot = s & 3;
    const int k0 = s * 32;
    gld_lds16(Abase + (size_t)r0 * HDIM + k0 + sc0 * 8, &As[slot][tid * 8]);
    gld_lds16(Abase + (size_t)r1 * HDIM + k0 + sc1 * 8,
              &As[slot][(tid + 256) * 8]);
    gld_lds16(Bbase + (size_t)r0 * HDIM + k0 + sc0 * 8, &Bs[slot][tid * 8]);
    gld_lds16(Bbase + (size_t)r1 * HDIM + k0 + sc1 * 8,
              &Bs[slot][(tid + 256) * 8]);
  };

  auto compute = [&](int s) {
    const int slot = s & 3;
    s16x8 af[4], bf[4];
#pragma unroll
    for (int m = 0; m < 4; ++m) {
      const int row = wr * 64 + m * 16 + l15;
      const int pc = l4 ^ ((row >> 1) & 3);
      af[m] = *(const s16x8*)&As[slot][row * 32 + pc * 8];
    }
#pragma unroll
    for (int n = 0; n < 4; ++n) {
      const int row = wc * 64 + n * 16 + l15;
      const int pc = l4 ^ ((row >> 1) & 3);
      bf[n] = *(const s16x8*)&Bs[slot][row * 32 + pc * 8];
    }
    if (s < 29) stage(s + 3);
#pragma unroll
    for (int m = 0; m < 4; ++m)
#pragma unroll
      for (int n = 0; n < 4; ++n)
        acc[m][n] = __builtin_amdgcn_mfma_f32_16x16x32_bf16(af[m], bf[n],
                                                            acc[m][n], 0, 0, 0);
  };

  stage(0); stage(1); stage(2);

#pragma unroll 1
  for (int s = 0; s < 30; ++s) {
    asm volatile("s_waitcnt vmcnt(8)" ::: "memory");
    asm volatile("s_barrier" ::: "memory");
    compute(s);
  }
  asm volatile("s_waitcnt vmcnt(4)" ::: "memory");
  asm volatile("s_barrier" ::: "memory");
  compute(30);
  asm volatile("s_waitcnt vmcnt(0)" ::: "memory");
  asm volatile("s_barrier" ::: "memory");
  compute(31);

#pragma unroll
  for (int n = 0; n < 4; ++n) {
    int col = bcol + wc * 64 + n * 16 + l15;
    float bv = bias[col];
#pragma unroll
    for (int m = 0; m < 4; ++m) {
      int row0 = brow + wr * 64 + m * 16 + l4 * 4;
      if (mode == 0) {
#pragma unroll
        for (int j = 0; j < 4; ++j)
          C[(size_t)(row0 + j) * HDIM + col] = f2bf(acc[m][n][j] + bv);
      } else {
        u16x4 o;
#pragma unroll
        for (int j = 0; j < 4; ++j) o[j] = f2bf(acc[m][n][j] + bv);
        *(u16x4*)(C + (size_t)(((row0 >> 11) << 10) + col) * SLEN +
                  (row0 & (SLEN - 1))) = o;
      }
    }
  }
}

__global__ __launch_bounds__(256) void gemm_bt(const u16* __restrict__ A,
                                               const u16* __restrict__ W,
                                               const float* __restrict__ bias,
                                               u16* __restrict__ C) {
  gemm_body(A, W, bias, C, 0);
}

__global__ __launch_bounds__(256) void gemm_kv(const u16* __restrict__ A,
                                               const u16* __restrict__ Wk,
                                               const float* __restrict__ bk,
                                               u16* __restrict__ K,
                                               const u16* __restrict__ Wv,
                                               const float* __restrict__ bv,
                                               u16* __restrict__ Vt) {
  if (blockIdx.z == 0) gemm_body(A, Wk, bk, K, 0);
  else                 gemm_body(A, Wv, bv, Vt, 1);
}

// ---------------- Flash attention v11: 64 q-rows/wave, shared fragments ----
// 256 thr / 4 waves, wave owns 64 q-rows (two 32-q blocks). Each LDS K/V
// fragment is read ONCE and feeds both q-blocks -> per-q LDS reads halved.
__global__ __launch_bounds__(256, 2) void attn_kernel(
    const u16* __restrict__ Qs, const u16* __restrict__ Kb,
    const u16* __restrict__ Vtg, const float* __restrict__ m2g,
    const float* __restrict__ flagp, float* __restrict__ out) {
  __shared__ u16 Ks[2][64 * 64];
  __shared__ u16 Vts[2][64 * 64];

  const int tid = threadIdx.x;
  const int lane = tid & 63;
  const int w = tid >> 6;          // 0..3
  // XCD-chunked bijective swizzle (512 blocks, 64 per XCD; 8 bh per XCD)
  const int bid = blockIdx.x;
  const int swz = (bid & 7) * 64 + (bid >> 3);
  const int qt = swz & 7;          // 2048/256 q-tiles
  const int bh = swz >> 3;
  const int b = bh >> 4, h = bh & 15;
  const int l31 = lane & 31;
  const int h1 = lane >> 5;        // 0/1

  const float4 fl = *(const float4*)flagp;
  const bool mz = (fl.x == 0.f && fl.y == 0.f && fl.z == 0.f && fl.w == 0.f);

  // Q fragments for two q-blocks: rows q0+l31 and q0+32+l31
  const int q0 = qt * 256 + w * 64;
  s16x8 qfa[4], qfb[4];
  {
    const u16* qpa = Qs + (size_t)(b * SLEN + q0 + l31) * HDIM + h * DHEAD + h1 * 8;
    const u16* qpb = qpa + (size_t)32 * HDIM;
#pragma unroll
    for (int dch = 0; dch < 4; ++dch) {
      qfa[dch] = *(const s16x8*)(qpa + dch * 16);
      qfb[dch] = *(const s16x8*)(qpb + dch * 16);
    }
  }

  const s16x8 onesf = {(short)0x3F80, (short)0x3F80, (short)0x3F80,
                       (short)0x3F80, (short)0x3F80, (short)0x3F80,
                       (short)0x3F80, (short)0x3F80};

  const float zf = fl.x * 0.0f;    // opaque zero

  // staging: 512 16B-chunks per 64x64 tile, 2 per thread for each of K, V
  const int r0 = tid >> 3, c0 = tid & 7;
  const int cl0 = c0 ^ (r0 & 7);
  const int r1 = r0 + 32;
  const int cl1 = c0 ^ (r1 & 7);
  const u16* Kbase = Kb + (size_t)(b * SLEN) * HDIM + h * DHEAD;
  const u16* Vbase = Vtg + (size_t)bh * 64 * SLEN;
  const float* mbase = m2g + b * SLEN;
  const u16* KstA = Kbase + (size_t)r0 * HDIM + cl0 * 8;
  const u16* KstB = Kbase + (size_t)r1 * HDIM + cl1 * 8;
  const u16* VstA = Vbase + (size_t)r0 * SLEN + cl0 * 8;
  const u16* VstB = Vbase + (size_t)r1 * SLEN + cl1 * 8;

  f32x16 acc0a{}, acc1a{}, acc_sa{};
  f32x16 acc0b{}, acc1b{}, acc_sb{};

  auto stage = [&](u16* Kd, u16* Vd, int kbn) {
    const size_t ko = (size_t)kbn * 64 * HDIM;
    const int vo = kbn * 64;
    gld_lds16(KstA + ko, Kd + tid * 8);
    gld_lds16(KstB + ko, Kd + (tid + 256) * 8);
    gld_lds16(VstA + vo, Vd + tid * 8);
    gld_lds16(VstB + vo, Vd + (tid + 256) * 8);
  };

  auto tile = [&](const u16* Kc, const u16* Vc, int kb) {
    uint32_t Wa[16], Wb[16];
#pragma unroll
    for (int kblk = 0; kblk < 2; ++kblk) {
      // shared C-init (mask depends on k only -> same for both q-blocks)
      f32x16 cinit;
      if (mz) {
#pragma unroll
        for (int i = 0; i < 16; ++i) cinit[i] = zf;
      } else {
#pragma unroll
        for (int g = 0; g < 4; ++g) {
          float4 mk =
              *(const float4*)(mbase + kb * 64 + kblk * 32 + g * 8 + h1 * 4);
          cinit[4 * g + 0] = mk.x; cinit[4 * g + 1] = mk.y;
          cinit[4 * g + 2] = mk.z; cinit[4 * g + 3] = mk.w;
        }
      }
      const int row = kblk * 32 + l31;
      // K fragments read ONCE, feed both q-blocks
      s16x8 kf[4];
#pragma unroll
      for (int dch = 0; dch < 4; ++dch) {
        const int ch = (dch * 2 + h1) ^ (row & 7);
        kf[dch] = *(const s16x8*)(Kc + row * 64 + ch * 8);
      }
      __builtin_amdgcn_s_setprio(1);
      f32x16 sTa = __builtin_amdgcn_mfma_f32_32x32x16_bf16(kf[0], qfa[0], cinit, 0, 0, 0);
#pragma unroll
      for (int dch = 1; dch < 4; ++dch)
        sTa = __builtin_amdgcn_mfma_f32_32x32x16_bf16(kf[dch], qfa[dch], sTa, 0, 0, 0);
      f32x16 sTb = __builtin_amdgcn_mfma_f32_32x32x16_bf16(kf[0], qfb[0], cinit, 0, 0, 0);
#pragma unroll
      for (int dch = 1; dch < 4; ++dch)
        sTb = __builtin_amdgcn_mfma_f32_32x32x16_bf16(kf[dch], qfb[dch], sTb, 0, 0, 0);
      __builtin_amdgcn_s_setprio(0);
#pragma unroll
      for (int g = 0; g < 4; ++g) {
        float a0 = __builtin_amdgcn_exp2f(sTa[4 * g + 0]);
        float a1 = __builtin_amdgcn_exp2f(sTa[4 * g + 1]);
        float a2 = __builtin_amdgcn_exp2f(sTa[4 * g + 2]);
        float a3 = __builtin_amdgcn_exp2f(sTa[4 * g + 3]);
        Wa[kblk * 8 + 2 * g]     = cvtpk2(a0, a1);
        Wa[kblk * 8 + 2 * g + 1] = cvtpk2(a2, a3);
        float b0 = __builtin_amdgcn_exp2f(sTb[4 * g + 0]);
        float b1 = __builtin_amdgcn_exp2f(sTb[4 * g + 1]);
        float b2 = __builtin_amdgcn_exp2f(sTb[4 * g + 2]);
        float b3 = __builtin_amdgcn_exp2f(sTb[4 * g + 3]);
        Wb[kblk * 8 + 2 * g]     = cvtpk2(b0, b1);
        Wb[kblk * 8 + 2 * g + 1] = cvtpk2(b2, b3);
      }
    }

    // half-exchange across lane-32 boundary
#pragma unroll
    for (int c = 0; c < 4; ++c) {
#pragma unroll
      for (int e = 0; e < 2; ++e) {
        uint32_t xa = Wa[4 * c + e], ya = Wa[4 * c + 2 + e];
        asm("v_permlane32_swap_b32 %0, %1" : "+v"(xa), "+v"(ya));
        Wa[4 * c + e] = xa; Wa[4 * c + 2 + e] = ya;
        uint32_t xb = Wb[4 * c + e], yb = Wb[4 * c + 2 + e];
        asm("v_permlane32_swap_b32 %0, %1" : "+v"(xb), "+v"(yb));
        Wb[4 * c + e] = xb; Wb[4 * c + 2 + e] = yb;
      }
    }

    // PV + row-sum: V fragments read ONCE, feed both q-blocks
    __builtin_amdgcn_s_setprio(1);
#pragma unroll
    for (int c = 0; c < 4; ++c) {
      u32x4 ta = {Wa[4 * c], Wa[4 * c + 1], Wa[4 * c + 2], Wa[4 * c + 3]};
      s16x8 afa = __builtin_bit_cast(s16x8, ta);
      u32x4 tb = {Wb[4 * c], Wb[4 * c + 1], Wb[4 * c + 2], Wb[4 * c + 3]};
      s16x8 afb = __builtin_bit_cast(s16x8, tb);
      const int ch = (c * 2 + h1) ^ (l31 & 7);
      s16x8 vf0 = *(const s16x8*)(Vc + l31 * 64 + ch * 8);
      s16x8 vf1 = *(const s16x8*)(Vc + (32 + l31) * 64 + ch * 8);
      acc0a = __builtin_amdgcn_mfma_f32_32x32x16_bf16(afa, vf0, acc0a, 0, 0, 0);
      acc1a = __builtin_amdgcn_mfma_f32_32x32x16_bf16(afa, vf1, acc1a, 0, 0, 0);
      acc_sa = __builtin_amdgcn_mfma_f32_32x32x16_bf16(afa, onesf, acc_sa, 0, 0, 0);
      acc0b = __builtin_amdgcn_mfma_f32_32x32x16_bf16(afb, vf0, acc0b, 0, 0, 0);
      acc1b = __builtin_amdgcn_mfma_f32_32x32x16_bf16(afb, vf1, acc1b, 0, 0, 0);
      acc_sb = __builtin_amdgcn_mfma_f32_32x32x16_bf16(afb, onesf, acc_sb, 0, 0, 0);
    }
    __builtin_amdgcn_s_setprio(0);
  };

  stage(&Ks[0][0], &Vts[0][0], 0);
  __syncthreads();

#pragma unroll 1
  for (int t = 0; t < 15; ++t) {
    stage(&Ks[1][0], &Vts[1][0], 2 * t + 1);
    tile(&Ks[0][0], &Vts[0][0], 2 * t);
    __syncthreads();
    stage(&Ks[0][0], &Vts[0][0], 2 * t + 2);
    tile(&Ks[1][0], &Vts[1][0], 2 * t + 1);
    __syncthreads();
  }
  stage(&Ks[1][0], &Vts[1][0], 31);
  tile(&Ks[0][0], &Vts[0][0], 30);
  __syncthreads();
  tile(&Ks[1][0], &Vts[1][0], 31);

  // epilogue: q-block A rows q0+qr, q-block B rows q0+32+qr
  const size_t obase = (size_t)(b * SLEN + q0);
#pragma unroll
  for (int r = 0; r < 16; ++r) {
    const int qr = (r & 3) + 8 * (r >> 2) + 4 * h1;
    const float sia = 1.0f / acc_sa[r];
    float* opa = out + (obase + qr) * HDIM + h * DHEAD;
    opa[l31]      = acc0a[r] * sia;
    opa[32 + l31] = acc1a[r] * sia;
    const float sib = 1.0f / acc_sb[r];
    float* opb = out + (obase + 32 + qr) * HDIM + h * DHEAD;
    opb[l31]      = acc0b[r] * sib;
    opb[32 + l31] = acc1b[r] * sib;
  }
}

extern "C" void kernel_launch(void* const* d_in, const int* in_sizes, int n_in,
                              void* d_out, int out_size, void* d_ws, size_t ws_size,
                              hipStream_t stream) {
  (void)in_sizes; (void)n_in; (void)out_size; (void)ws_size;
  const float* hs   = (const float*)d_in[0];
  const float* mask = (const float*)d_in[1];
  const float* Wq   = (const float*)d_in[2];
  const float* bq   = (const float*)d_in[3];
  const float* Wk   = (const float*)d_in[4];
  const float* bk   = (const float*)d_in[5];
  const float* Wv   = (const float*)d_in[6];
  const float* bv   = (const float*)d_in[7];
  float* out = (float*)d_out;

  char* ws = (char*)d_ws;
  const size_t MTOK = (size_t)BATCH * SLEN;  // 8192
  const size_t MB = 1024 * 1024;
  u16* HSb = (u16*)ws;                       // 16MB
  u16* Wqs = (u16*)(ws + 16 * MB);           // 2MB each (scaled)
  u16* Wks = (u16*)(ws + 18 * MB);
  u16* Wvs = (u16*)(ws + 20 * MB);
  u16* Qs  = (u16*)(ws + 22 * MB);           // 16MB scaled mixed_q
  u16* Kb  = (u16*)(ws + 38 * MB);           // 16MB
  u16* Vt  = (u16*)(ws + 54 * MB);           // 16MB transposed V
  float* m2  = (float*)(ws + 70 * MB);       // 32KB
  float* bqs = m2 + MTOK;                    // 4KB
  float* flg = bqs + 1024;                   // 16B

  prep_all<<<11298, 256, 0, stream>>>((const float4*)hs, (const float4*)Wq,
                                      (const float4*)Wk, (const float4*)Wv,
                                      mask, bq, HSb, Wqs, Wks, Wvs, m2, bqs, flg);

  dim3 gg(HDIM / 128, MTOK / 128);       // (8, 64)
  gemm_bt<<<gg, 256, 0, stream>>>(HSb, Wqs, bqs, Qs);
  dim3 gkv(HDIM / 128, MTOK / 128, 2);
  gemm_kv<<<gkv, 256, 0, stream>>>(Qs, Wks, bk, Kb, Wvs, bv, Vt);

  attn_kernel<<<BATCH * NHEAD * (SLEN / 256), 256, 0, stream>>>(Qs, Kb, Vt, m2,
                                                                flg, out);
}

// Round 14
// 163.511 us; speedup vs baseline: 1.1493x; 1.0067x over previous
//
#include <hip/hip_runtime.h>
#include <stdint.h>

typedef float  f32x4  __attribute__((ext_vector_type(4)));
typedef float  f32x16 __attribute__((ext_vector_type(16)));
typedef short  s16x8  __attribute__((ext_vector_type(8)));
typedef unsigned int u32x4 __attribute__((ext_vector_type(4)));
typedef unsigned short u16;
typedef u16    u16x4 __attribute__((ext_vector_type(4)));

#define SLEN 2048
#define HDIM 1024
#define NHEAD 16
#define DHEAD 64
#define BATCH 4
#define LOG2E 1.44269504088896340736f
#define SC2   0.18033688011111772f   /* 0.125 * log2(e) */
#define ISC2  5.5451774444795623f    /* 1/SC2 */

__device__ __forceinline__ u16 f2bf(float f) {
  uint32_t u = __builtin_bit_cast(uint32_t, f);
  u += 0x7FFFu + ((u >> 16) & 1u);
  return (u16)(u >> 16);
}

__device__ __forceinline__ uint32_t cvtpk2(float a, float b) {
  uint32_t r;
  asm("v_cvt_pk_bf16_f32 %0, %1, %2" : "=v"(r) : "v"(a), "v"(b));
  return r;
}

__device__ __forceinline__ void gld_lds16(const void* g, void* l) {
  __builtin_amdgcn_global_load_lds(
      (const __attribute__((address_space(1))) unsigned int*)g,
      (__attribute__((address_space(3))) unsigned int*)l, 16, 0, 0);
}

// ---- fused prep: HS->bf16, 3 weights scaled->bf16, m2, bqs, mask-zero flag ----
__global__ __launch_bounds__(256) void prep_all(
    const float4* __restrict__ hs, const float4* __restrict__ W0,
    const float4* __restrict__ W1, const float4* __restrict__ W2,
    const float* __restrict__ mask, const float* __restrict__ bq,
    u16* __restrict__ HSb, u16* __restrict__ O0, u16* __restrict__ O1,
    u16* __restrict__ O2, float* __restrict__ m2, float* __restrict__ bqs,
    float* __restrict__ flagp) {
  const int bid = blockIdx.x, tid = threadIdx.x;
  if (bid < 8192) {                       // hidden states: 8M elems
    int i = bid * 256 + tid;
    float4 v = hs[i];
    u16x4 o;
    o.x = f2bf(v.x); o.y = f2bf(v.y); o.z = f2bf(v.z); o.w = f2bf(v.w);
    *(u16x4*)(HSb + (size_t)i * 4) = o;
  } else if (bid < 11264) {               // 3 weight matrices
    int zz = (bid - 8192) >> 10;
    int i = ((bid - 8192) & 1023) * 256 + tid;
    const float4* in = zz == 0 ? W0 : (zz == 1 ? W1 : W2);
    u16* out = zz == 0 ? O0 : (zz == 1 ? O1 : O2);
    const float sc = zz == 0 ? SC2 : ISC2;
    float4 v = in[i];
    u16x4 o;
    o.x = f2bf(v.x * sc); o.y = f2bf(v.y * sc);
    o.z = f2bf(v.z * sc); o.w = f2bf(v.w * sc);
    *(u16x4*)(out + (size_t)i * 4) = o;
  } else if (bid < 11296) {               // m2 = mask*LOG2E (8192 floats)
    int i = (bid - 11264) * 256 + tid;
    m2[i] = mask[i] * LOG2E;
  } else if (bid < 11297) {               // bqs = bq*SC2 (1024 floats)
#pragma unroll
    for (int k = 0; k < 4; ++k) bqs[tid + k * 256] = bq[tid + k * 256] * SC2;
  } else {                                // mask nonzero flag (4 floats)
    float a = 0.f;
#pragma unroll
    for (int k = 0; k < 32; ++k) a += __builtin_fabsf(mask[tid + k * 256]);
    int nz = __any(a != 0.f) ? 1 : 0;
    if ((tid & 63) == 0) flagp[tid >> 6] = (float)nz;
  }
}

// ---------------- GEMM: C[M,1024] = A @ W^T + bias ----------------
// 128x128 tile, BK=32, 4-slot LDS ring, counted vmcnt(8) (no drains),
// one raw s_barrier per sub-tile, XOR chunk swizzle, XCD-chunked blocks.
// MODE 0: row-major C. MODE 1: transposed-V layout Vt[(s>>11)*1024+col][s&2047]
__device__ __forceinline__ void gemm_body(const u16* __restrict__ A,
                                          const u16* __restrict__ W,
                                          const float* __restrict__ bias,
                                          u16* __restrict__ C, int mode) {
  __shared__ u16 As[4][128 * 32];
  __shared__ u16 Bs[4][128 * 32];
  const int tid = threadIdx.x;
  const int lane = tid & 63;
  const int w = tid >> 6;
  const int wr = w >> 1, wc = w & 1;
  // XCD-chunked bijective swizzle of the 512-block (x,y) grid (gridDim.x==8)
  const int flat = blockIdx.x + blockIdx.y * 8;
  const int swz = (flat & 7) * 64 + (flat >> 3);
  const int brow = (swz >> 3) * 128;
  const int bcol = (swz & 7) * 128;
  const int l15 = lane & 15, l4 = lane >> 4;

  const int r0 = tid >> 2, c0 = tid & 3;
  const int sc0 = c0 ^ ((r0 >> 1) & 3);
  const int r1 = r0 + 64;
  const int sc1 = c0 ^ ((r1 >> 1) & 3);
  const u16* Abase = A + (size_t)brow * HDIM;
  const u16* Bbase = W + (size_t)bcol * HDIM;

  f32x4 acc[4][4];
#pragma unroll
  for (int m = 0; m < 4; ++m)
#pragma unroll
    for (int n = 0; n < 4; ++n) acc[m][n] = f32x4{0.f, 0.f, 0.f, 0.f};

  auto stage = [&](int s) {
    const int slot = s & 3;
    const int k0 = s * 32;
    gld_lds16(Abase + (size_t)r0 * HDIM + k0 + sc0 * 8, &As[slot][tid * 8]);
    gld_lds16(Abase + (size_t)r1 * HDIM + k0 + sc1 * 8,
              &As[slot][(tid + 256) * 8]);
    gld_lds16(Bbase + (size_t)r0 * HDIM + k0 + sc0 * 8, &Bs[slot][tid * 8]);
    gld_lds16(Bbase + (size_t)r1 * HDIM + k0 + sc1 * 8,
              &Bs[slot][(tid + 256) * 8]);
  };

  auto compute = [&](int s) {
    const int slot = s & 3;
    s16x8 af[4], bf[4];
#pragma unroll
    for (int m = 0; m < 4; ++m) {
      const int row = wr * 64 + m * 16 + l15;
      const int pc = l4 ^ ((row >> 1) & 3);
      af[m] = *(const s16x8*)&As[slot][row * 32 + pc * 8];
    }
#pragma unroll
    for (int n = 0; n < 4; ++n) {
      const int row = wc * 64 + n * 16 + l15;
      const int pc = l4 ^ ((row >> 1) & 3);
      bf[n] = *(const s16x8*)&Bs[slot][row * 32 + pc * 8];
    }
    if (s < 29) stage(s + 3);
#pragma unroll
    for (int m = 0; m < 4; ++m)
#pragma unroll
      for (int n = 0; n < 4; ++n)
        acc[m][n] = __builtin_amdgcn_mfma_f32_16x16x32_bf16(af[m], bf[n],
                                                            acc[m][n], 0, 0, 0);
  };

  stage(0); stage(1); stage(2);

#pragma unroll 1
  for (int s = 0; s < 30; ++s) {
    asm volatile("s_waitcnt vmcnt(8)" ::: "memory");
    asm volatile("s_barrier" ::: "memory");
    compute(s);
  }
  asm volatile("s_waitcnt vmcnt(4)" ::: "memory");
  asm volatile("s_barrier" ::: "memory");
  compute(30);
  asm volatile("s_waitcnt vmcnt(0)" ::: "memory");
  asm volatile("s_barrier" ::: "memory");
  compute(31);

#pragma unroll
  for (int n = 0; n < 4; ++n) {
    int col = bcol + wc * 64 + n * 16 + l15;
    float bv = bias[col];
#pragma unroll
    for (int m = 0; m < 4; ++m) {
      int row0 = brow + wr * 64 + m * 16 + l4 * 4;
      if (mode == 0) {
#pragma unroll
        for (int j = 0; j < 4; ++j)
          C[(size_t)(row0 + j) * HDIM + col] = f2bf(acc[m][n][j] + bv);
      } else {
        u16x4 o;
#pragma unroll
        for (int j = 0; j < 4; ++j) o[j] = f2bf(acc[m][n][j] + bv);
        *(u16x4*)(C + (size_t)(((row0 >> 11) << 10) + col) * SLEN +
                  (row0 & (SLEN - 1))) = o;
      }
    }
  }
}

__global__ __launch_bounds__(256) void gemm_bt(const u16* __restrict__ A,
                                               const u16* __restrict__ W,
                                               const float* __restrict__ bias,
                                               u16* __restrict__ C) {
  gemm_body(A, W, bias, C, 0);
}

__global__ __launch_bounds__(256) void gemm_kv(const u16* __restrict__ A,
                                               const u16* __restrict__ Wk,
                                               const float* __restrict__ bk,
                                               u16* __restrict__ K,
                                               const u16* __restrict__ Wv,
                                               const float* __restrict__ bv,
                                               u16* __restrict__ Vt) {
  if (blockIdx.z == 0) gemm_body(A, Wk, bk, K, 0);
  else                 gemm_body(A, Wv, bv, Vt, 1);
}

// ---------------- Flash attention v12: 512 thr / 8 waves, 64 q-rows/wave ----
// 256 blocks. Staging: ONE K-chunk + ONE V-chunk per thread per tile (halved).
// Per-wave body identical to v11 (fragment sharing, in-register P, MFMA rowsum).
__global__ __launch_bounds__(512, 2) void attn_kernel(
    const u16* __restrict__ Qs, const u16* __restrict__ Kb,
    const u16* __restrict__ Vtg, const float* __restrict__ m2g,
    const float* __restrict__ flagp, float* __restrict__ out) {
  __shared__ u16 Ks[2][64 * 64];
  __shared__ u16 Vts[2][64 * 64];

  const int tid = threadIdx.x;
  const int lane = tid & 63;
  const int w = tid >> 6;          // 0..7
  // XCD-chunked bijective swizzle (256 blocks, 32 per XCD; 8 bh per XCD)
  const int bid = blockIdx.x;
  const int swz = (bid & 7) * 32 + (bid >> 3);
  const int qt = swz & 3;          // 2048/512 q-tiles
  const int bh = swz >> 2;
  const int b = bh >> 4, h = bh & 15;
  const int l31 = lane & 31;
  const int h1 = lane >> 5;        // 0/1

  const float4 fl = *(const float4*)flagp;
  const bool mz = (fl.x == 0.f && fl.y == 0.f && fl.z == 0.f && fl.w == 0.f);

  // Q fragments for two q-blocks: rows q0+l31 and q0+32+l31
  const int q0 = qt * 512 + w * 64;
  s16x8 qfa[4], qfb[4];
  {
    const u16* qpa = Qs + (size_t)(b * SLEN + q0 + l31) * HDIM + h * DHEAD + h1 * 8;
    const u16* qpb = qpa + (size_t)32 * HDIM;
#pragma unroll
    for (int dch = 0; dch < 4; ++dch) {
      qfa[dch] = *(const s16x8*)(qpa + dch * 16);
      qfb[dch] = *(const s16x8*)(qpb + dch * 16);
    }
  }

  const s16x8 onesf = {(short)0x3F80, (short)0x3F80, (short)0x3F80,
                       (short)0x3F80, (short)0x3F80, (short)0x3F80,
                       (short)0x3F80, (short)0x3F80};

  const float zf = fl.x * 0.0f;    // opaque zero

  // staging: 512 16B-chunks per 64x64 tile, ONE per thread for each of K, V
  const int r0 = tid >> 3, c0 = tid & 7;
  const int cl0 = c0 ^ (r0 & 7);
  const u16* Kbase = Kb + (size_t)(b * SLEN) * HDIM + h * DHEAD;
  const u16* Vbase = Vtg + (size_t)bh * 64 * SLEN;
  const float* mbase = m2g + b * SLEN;
  const u16* KstA = Kbase + (size_t)r0 * HDIM + cl0 * 8;
  const u16* VstA = Vbase + (size_t)r0 * SLEN + cl0 * 8;

  f32x16 acc0a{}, acc1a{}, acc_sa{};
  f32x16 acc0b{}, acc1b{}, acc_sb{};

  auto stage = [&](u16* Kd, u16* Vd, int kbn) {
    const size_t ko = (size_t)kbn * 64 * HDIM;
    const int vo = kbn * 64;
    gld_lds16(KstA + ko, Kd + tid * 8);
    gld_lds16(VstA + vo, Vd + tid * 8);
  };

  auto tile = [&](const u16* Kc, const u16* Vc, int kb) {
    uint32_t Wa[16], Wb[16];
#pragma unroll
    for (int kblk = 0; kblk < 2; ++kblk) {
      // shared C-init (mask depends on k only -> same for both q-blocks)
      f32x16 cinit;
      if (mz) {
#pragma unroll
        for (int i = 0; i < 16; ++i) cinit[i] = zf;
      } else {
#pragma unroll
        for (int g = 0; g < 4; ++g) {
          float4 mk =
              *(const float4*)(mbase + kb * 64 + kblk * 32 + g * 8 + h1 * 4);
          cinit[4 * g + 0] = mk.x; cinit[4 * g + 1] = mk.y;
          cinit[4 * g + 2] = mk.z; cinit[4 * g + 3] = mk.w;
        }
      }
      const int row = kblk * 32 + l31;
      // K fragments read ONCE, feed both q-blocks
      s16x8 kf[4];
#pragma unroll
      for (int dch = 0; dch < 4; ++dch) {
        const int ch = (dch * 2 + h1) ^ (row & 7);
        kf[dch] = *(const s16x8*)(Kc + row * 64 + ch * 8);
      }
      __builtin_amdgcn_s_setprio(1);
      f32x16 sTa = __builtin_amdgcn_mfma_f32_32x32x16_bf16(kf[0], qfa[0], cinit, 0, 0, 0);
#pragma unroll
      for (int dch = 1; dch < 4; ++dch)
        sTa = __builtin_amdgcn_mfma_f32_32x32x16_bf16(kf[dch], qfa[dch], sTa, 0, 0, 0);
      f32x16 sTb = __builtin_amdgcn_mfma_f32_32x32x16_bf16(kf[0], qfb[0], cinit, 0, 0, 0);
#pragma unroll
      for (int dch = 1; dch < 4; ++dch)
        sTb = __builtin_amdgcn_mfma_f32_32x32x16_bf16(kf[dch], qfb[dch], sTb, 0, 0, 0);
      __builtin_amdgcn_s_setprio(0);
#pragma unroll
      for (int g = 0; g < 4; ++g) {
        float a0 = __builtin_amdgcn_exp2f(sTa[4 * g + 0]);
        float a1 = __builtin_amdgcn_exp2f(sTa[4 * g + 1]);
        float a2 = __builtin_amdgcn_exp2f(sTa[4 * g + 2]);
        float a3 = __builtin_amdgcn_exp2f(sTa[4 * g + 3]);
        Wa[kblk * 8 + 2 * g]     = cvtpk2(a0, a1);
        Wa[kblk * 8 + 2 * g + 1] = cvtpk2(a2, a3);
        float b0 = __builtin_amdgcn_exp2f(sTb[4 * g + 0]);
        float b1 = __builtin_amdgcn_exp2f(sTb[4 * g + 1]);
        float b2 = __builtin_amdgcn_exp2f(sTb[4 * g + 2]);
        float b3 = __builtin_amdgcn_exp2f(sTb[4 * g + 3]);
        Wb[kblk * 8 + 2 * g]     = cvtpk2(b0, b1);
        Wb[kblk * 8 + 2 * g + 1] = cvtpk2(b2, b3);
      }
    }

    // half-exchange across lane-32 boundary
#pragma unroll
    for (int c = 0; c < 4; ++c) {
#pragma unroll
      for (int e = 0; e < 2; ++e) {
        uint32_t xa = Wa[4 * c + e], ya = Wa[4 * c + 2 + e];
        asm("v_permlane32_swap_b32 %0, %1" : "+v"(xa), "+v"(ya));
        Wa[4 * c + e] = xa; Wa[4 * c + 2 + e] = ya;
        uint32_t xb = Wb[4 * c + e], yb = Wb[4 * c + 2 + e];
        asm("v_permlane32_swap_b32 %0, %1" : "+v"(xb), "+v"(yb));
        Wb[4 * c + e] = xb; Wb[4 * c + 2 + e] = yb;
      }
    }

    // PV + row-sum: V fragments read ONCE, feed both q-blocks
    __builtin_amdgcn_s_setprio(1);
#pragma unroll
    for (int c = 0; c < 4; ++c) {
      u32x4 ta = {Wa[4 * c], Wa[4 * c + 1], Wa[4 * c + 2], Wa[4 * c + 3]};
      s16x8 afa = __builtin_bit_cast(s16x8, ta);
      u32x4 tb = {Wb[4 * c], Wb[4 * c + 1], Wb[4 * c + 2], Wb[4 * c + 3]};
      s16x8 afb = __builtin_bit_cast(s16x8, tb);
      const int ch = (c * 2 + h1) ^ (l31 & 7);
      s16x8 vf0 = *(const s16x8*)(Vc + l31 * 64 + ch * 8);
      s16x8 vf1 = *(const s16x8*)(Vc + (32 + l31) * 64 + ch * 8);
      acc0a = __builtin_amdgcn_mfma_f32_32x32x16_bf16(afa, vf0, acc0a, 0, 0, 0);
      acc1a = __builtin_amdgcn_mfma_f32_32x32x16_bf16(afa, vf1, acc1a, 0, 0, 0);
      acc_sa = __builtin_amdgcn_mfma_f32_32x32x16_bf16(afa, onesf, acc_sa, 0, 0, 0);
      acc0b = __builtin_amdgcn_mfma_f32_32x32x16_bf16(afb, vf0, acc0b, 0, 0, 0);
      acc1b = __builtin_amdgcn_mfma_f32_32x32x16_bf16(afb, vf1, acc1b, 0, 0, 0);
      acc_sb = __builtin_amdgcn_mfma_f32_32x32x16_bf16(afb, onesf, acc_sb, 0, 0, 0);
    }
    __builtin_amdgcn_s_setprio(0);
  };

  stage(&Ks[0][0], &Vts[0][0], 0);
  __syncthreads();

#pragma unroll 1
  for (int t = 0; t < 15; ++t) {
    stage(&Ks[1][0], &Vts[1][0], 2 * t + 1);
    tile(&Ks[0][0], &Vts[0][0], 2 * t);
    __syncthreads();
    stage(&Ks[0][0], &Vts[0][0], 2 * t + 2);
    tile(&Ks[1][0], &Vts[1][0], 2 * t + 1);
    __syncthreads();
  }
  stage(&Ks[1][0], &Vts[1][0], 31);
  tile(&Ks[0][0], &Vts[0][0], 30);
  __syncthreads();
  tile(&Ks[1][0], &Vts[1][0], 31);

  // epilogue: q-block A rows q0+qr, q-block B rows q0+32+qr
  const size_t obase = (size_t)(b * SLEN + q0);
#pragma unroll
  for (int r = 0; r < 16; ++r) {
    const int qr = (r & 3) + 8 * (r >> 2) + 4 * h1;
    const float sia = 1.0f / acc_sa[r];
    float* opa = out + (obase + qr) * HDIM + h * DHEAD;
    opa[l31]      = acc0a[r] * sia;
    opa[32 + l31] = acc1a[r] * sia;
    const float sib = 1.0f / acc_sb[r];
    float* opb = out + (obase + 32 + qr) * HDIM + h * DHEAD;
    opb[l31]      = acc0b[r] * sib;
    opb[32 + l31] = acc1b[r] * sib;
  }
}

extern "C" void kernel_launch(void* const* d_in, const int* in_sizes, int n_in,
                              void* d_out, int out_size, void* d_ws, size_t ws_size,
                              hipStream_t stream) {
  (void)in_sizes; (void)n_in; (void)out_size; (void)ws_size;
  const float* hs   = (const float*)d_in[0];
  const float* mask = (const float*)d_in[1];
  const float* Wq   = (const float*)d_in[2];
  const float* bq   = (const float*)d_in[3];
  const float* Wk   = (const float*)d_in[4];
  const float* bk   = (const float*)d_in[5];
  const float* Wv   = (const float*)d_in[6];
  const float* bv   = (const float*)d_in[7];
  float* out = (float*)d_out;

  char* ws = (char*)d_ws;
  const size_t MTOK = (size_t)BATCH * SLEN;  // 8192
  const size_t MB = 1024 * 1024;
  u16* HSb = (u16*)ws;                       // 16MB
  u16* Wqs = (u16*)(ws + 16 * MB);           // 2MB each (scaled)
  u16* Wks = (u16*)(ws + 18 * MB);
  u16* Wvs = (u16*)(ws + 20 * MB);
  u16* Qs  = (u16*)(ws + 22 * MB);           // 16MB scaled mixed_q
  u16* Kb  = (u16*)(ws + 38 * MB);           // 16MB
  u16* Vt  = (u16*)(ws + 54 * MB);           // 16MB transposed V
  float* m2  = (float*)(ws + 70 * MB);       // 32KB
  float* bqs = m2 + MTOK;                    // 4KB
  float* flg = bqs + 1024;                   // 16B

  prep_all<<<11298, 256, 0, stream>>>((const float4*)hs, (const float4*)Wq,
                                      (const float4*)Wk, (const float4*)Wv,
                                      mask, bq, HSb, Wqs, Wks, Wvs, m2, bqs, flg);

  dim3 gg(HDIM / 128, MTOK / 128);       // (8, 64)
  gemm_bt<<<gg, 256, 0, stream>>>(HSb, Wqs, bqs, Qs);
  dim3 gkv(HDIM / 128, MTOK / 128, 2);
  gemm_kv<<<gkv, 256, 0, stream>>>(Qs, Wks, bk, Kb, Wvs, bv, Vt);

  attn_kernel<<<BATCH * NHEAD * (SLEN / 512), 512, 0, stream>>>(Qs, Kb, Vt, m2,
                                                                flg, out);
}